// Round 9
// baseline (107.446 us; speedup 1.0000x reference)
//
#include <hip/hip_runtime.h>
#include <hip/hip_bf16.h>
#include <math.h>

#define NROWS 16384
#define DIN   784
#define DZ    100
#define NS    10
#define NCT   16           // 16 col-tiles x 16 = 256 cols (200 real + 56 zero pad)
#define KTILES 25          // 25 * 32 = 800 >= 784
#define KT2   28           // Wb padded to 28 kts so 4-way K-split runs 7 uniform steps
#define BND_THR 45.0f

typedef unsigned short ushort_t;
typedef short bf16x8 __attribute__((ext_vector_type(8)));
typedef float f32x4  __attribute__((ext_vector_type(4)));

#define AS1 __attribute__((address_space(1)))
#define AS3 __attribute__((address_space(3)))

// ws layout (float offsets):
//  [0..199]   colsum softplus (atomic)   [200] pv log-sum (atomic)   [201] Dkl
//  [208..8047]  y2[s][i] = y * log2e     [8064..9063] z[s][d]
//  [16384..]  Wb: bf16 fragment-swizzled W, 28*16*512 ushorts (458 KB)
#define WS_Y2 208
#define WS_Z  8064
#define WS_WB 16384

__device__ __forceinline__ float softplusf(float v) {
    return fmaxf(v, 0.f) + log1pf(__expf(-fabsf(v)));
}
__device__ __forceinline__ unsigned pack2(float lo, float hi) {
    float2 f2; f2.x = lo; f2.y = hi;
    __hip_bfloat162 h2 = __float22bfloat162_rn(f2);
    return *reinterpret_cast<unsigned*>(&h2);
}
__device__ __forceinline__ void glds16(const float* src, void* dst) {
    __builtin_amdgcn_global_load_lds((const AS1 unsigned*)src, (AS3 unsigned*)dst, 16, 0, 0);
}
__device__ __forceinline__ void glds16u(const ushort_t* src, void* dst) {
    __builtin_amdgcn_global_load_lds((const AS1 unsigned*)src, (AS3 unsigned*)dst, 16, 0, 0);
}

// ---- W -> bf16, pre-swizzled to MFMA B-fragment order, kt padded to 28 ----
// Wb[((kt*16 + ct)*64 + l)*8 + j] = W[ct*16 + (l&15)][kt*32 + (l>>4)*8 + j]
__global__ __launch_bounds__(256) void wb2_kernel(
    const float* __restrict__ W0, const float* __restrict__ W1, ushort_t* __restrict__ Wb)
{
    int t = blockIdx.x * 256 + threadIdx.x;
    if (t >= KT2 * NCT * 64) return;
    int kt = t >> 10;
    int r  = t & 1023;
    int ct = r >> 6, l = r & 63;
    int col = ct * 16 + (l & 15);
    int k0  = kt * 32 + (l >> 4) * 8;
    uint4 o = make_uint4(0u, 0u, 0u, 0u);
    if (col < 200 && k0 < DIN) {
        const float* src = (col < 100 ? W0 + (size_t)col * DIN
                                      : W1 + (size_t)(col - 100) * DIN) + k0;
        float4 a = *(const float4*)src;
        float4 b = *(const float4*)(src + 4);
        o.x = pack2(a.x, a.y); o.y = pack2(a.z, a.w);
        o.z = pack2(b.x, b.y); o.w = pack2(b.z, b.w);
    }
    *(uint4*)(Wb + (size_t)t * 8) = o;
}

// ---- colmean v2: R5-pv-style. 2048 blocks x 4 waves; block = 32 rows x 4 tiles.
// Waves K-split (kt = w, w+4, ..., w+24; 7 steps). NO barriers in K-loop;
// register dbuf pinned with sched_barrier. Cross-wave LDS reduce (stride-33 pad).
#define RED(ws_, l_, c_) red[(((ws_) * 64) + (l_)) * 33 + (c_)]
__global__ __launch_bounds__(256, 4) void colmean_v2(
    const float* __restrict__ x, const ushort_t* __restrict__ Wb,
    const float* __restrict__ b0, const float* __restrict__ b1,
    float* __restrict__ ws)
{
    __shared__ float red[2 * 64 * 33];     // 16.9 KB
    const int tid = threadIdx.x;
    const int lane = tid & 63, w = tid >> 6;

    int b = blockIdx.x;                    // XCD-bijective: 2048 = 8 * 256
    int logical = (b & 7) * 256 + (b >> 3);
    const int strip = logical >> 2, q = logical & 3;

    const float* xr0 = x + (size_t)(strip * 32 + (lane & 15)) * DIN;
    const float* xr1 = xr0 + (size_t)16 * DIN;
    const int kc = lane >> 4;

    f32x4 acc[2][4];
#pragma unroll
    for (int rg = 0; rg < 2; ++rg)
#pragma unroll
        for (int jj = 0; jj < 4; ++jj) acc[rg][jj] = (f32x4){0.f, 0.f, 0.f, 0.f};

    float4 Aa[4], Ab[4];
    uint4  Ba[4], Bb[4];

    auto loadA = [&](int kt, float4 (&A)[4]) {
        int k0 = kt * 32 + kc * 8;
        if (k0 + 8 > DIN) k0 = 768;        // junk ok: W frags zero at k>=784 / kt>=25
        A[0] = *(const float4*)(xr0 + k0);
        A[1] = *(const float4*)(xr0 + k0 + 4);
        A[2] = *(const float4*)(xr1 + k0);
        A[3] = *(const float4*)(xr1 + k0 + 4);
    };
    auto loadB = [&](int kt, uint4 (&B)[4]) {
#pragma unroll
        for (int jj = 0; jj < 4; ++jj)
            B[jj] = *(const uint4*)(Wb + ((size_t)((kt * NCT + q * 4 + jj) * 64 + lane)) * 8);
    };
    auto comp = [&](const float4 (&A)[4], const uint4 (&B)[4]) {
#pragma unroll
        for (int rg = 0; rg < 2; ++rg) {
            bf16x8 af; unsigned* p = (unsigned*)&af;
            p[0] = pack2(A[2 * rg].x, A[2 * rg].y);
            p[1] = pack2(A[2 * rg].z, A[2 * rg].w);
            p[2] = pack2(A[2 * rg + 1].x, A[2 * rg + 1].y);
            p[3] = pack2(A[2 * rg + 1].z, A[2 * rg + 1].w);
#pragma unroll
            for (int jj = 0; jj < 4; ++jj)
                acc[rg][jj] = __builtin_amdgcn_mfma_f32_16x16x32_bf16(
                    af, *(const bf16x8*)&B[jj], acc[rg][jj], 0, 0, 0);
        }
    };

    loadA(w, Aa); loadB(w, Ba);
#pragma unroll
    for (int i = 0; i < 3; ++i) {
        loadA(w + 4 * (2 * i + 1), Ab); loadB(w + 4 * (2 * i + 1), Bb);
        __builtin_amdgcn_sched_barrier(0);     // keep prefetch above the MFMAs
        comp(Aa, Ba);
        loadA(w + 4 * (2 * i + 2), Aa); loadB(w + 4 * (2 * i + 2), Ba);
        __builtin_amdgcn_sched_barrier(0);
        comp(Ab, Bb);
    }
    comp(Aa, Ba);                              // step 7: kt = w + 24

    // cross-wave K reduce
    if (w >= 2) {
#pragma unroll
        for (int rg = 0; rg < 2; ++rg)
#pragma unroll
            for (int jj = 0; jj < 4; ++jj)
#pragma unroll
                for (int r = 0; r < 4; ++r)
                    RED(w - 2, lane, rg * 16 + jj * 4 + r) = acc[rg][jj][r];
    }
    __syncthreads();
    if (w < 2) {
#pragma unroll
        for (int rg = 0; rg < 2; ++rg)
#pragma unroll
            for (int jj = 0; jj < 4; ++jj)
#pragma unroll
                for (int r = 0; r < 4; ++r)
                    acc[rg][jj][r] += RED(w, lane, rg * 16 + jj * 4 + r);
    }
    __syncthreads();
    if (w == 1) {
#pragma unroll
        for (int rg = 0; rg < 2; ++rg)
#pragma unroll
            for (int jj = 0; jj < 4; ++jj)
#pragma unroll
                for (int r = 0; r < 4; ++r)
                    RED(0, lane, rg * 16 + jj * 4 + r) = acc[rg][jj][r];
    }
    __syncthreads();
    if (w == 0) {
#pragma unroll
        for (int jj = 0; jj < 4; ++jj) {
            int j = (q * 4 + jj) * 16 + (lane & 15);
            float bias = (j < 100) ? b0[j] : ((j < 200) ? b1[j - 100] : 0.f);
            float v = 0.f;
#pragma unroll
            for (int rg = 0; rg < 2; ++rg)
#pragma unroll
                for (int r = 0; r < 4; ++r)
                    v += softplusf(acc[rg][jj][r] + RED(0, lane, rg * 16 + jj * 4 + r) + bias);
            v += __shfl_xor(v, 16);
            v += __shfl_xor(v, 32);
            if ((lane >> 4) == 0 && j < 200) atomicAdd(&ws[j], v);
        }
    }
}

// ---- mean/cov, z, Dkl (single block) ----
__global__ __launch_bounds__(256) void middle_kernel(
    const float* __restrict__ eps, float* __restrict__ ws)
{
    __shared__ float red[256];
    const int tid = threadIdx.x;
    float contrib = 0.f;
    if (tid < DZ) {
        const float inv = 1.f / (float)NROWS;
        float mm = ws[tid] * inv;
        float cc = ws[100 + tid] * inv;
        contrib = 0.5f * __logf(cc);
#pragma unroll
        for (int s = 0; s < NS; ++s) {
            float e = eps[s * DZ + tid];
            float zz = mm + cc * e;
            ws[WS_Z + s * DZ + tid] = zz;
            contrib += (0.5f * cc * e * e - 0.5f * zz * zz) * (1.f / NS);
        }
    }
    red[tid] = contrib;
    __syncthreads();
    for (int off = 128; off > 0; off >>= 1) {
        if (tid < off) red[tid] += red[tid + off];
        __syncthreads();
    }
    if (tid == 0) ws[201] = red[0];
}

// ---- y2 = (z @ W2.T + b2) * log2e ----
__global__ __launch_bounds__(256) void y2_kernel(
    const float* __restrict__ W2, const float* __restrict__ b2,
    float* __restrict__ ws)
{
    int wid  = (int)((blockIdx.x * 256 + threadIdx.x) >> 6);
    int lane = threadIdx.x & 63;
    if (wid >= NS * DIN) return;
    int s = wid / DIN, i = wid % DIN;
    const float* zz = ws + WS_Z + s * DZ;
    const float* wr = W2 + (size_t)i * DZ;
    float p = 0.f;
    for (int d = lane; d < DZ; d += 64) p += zz[d] * wr[d];
#pragma unroll
    for (int off = 32; off > 0; off >>= 1) p += __shfl_xor(p, off);
    if (lane == 0) ws[WS_Y2 + wid] = (p + b2[i]) * 1.4426950408889634f;
}

// ---- pv: R5 version (fast). MFMA-certified bound + rare honest fallback ----
__global__ __launch_bounds__(256, 4) void pv_kernel(
    const float* __restrict__ x, const float* ws, float* out_sum)
{
    __shared__ ushort_t yf[KTILES * 512];   // y2 B-frags (bf16)
    __shared__ ushort_t ya[KTILES * 512];   // |y2| B-frags
    __shared__ float bsum;
    const int tid = threadIdx.x;
    const int lane = tid & 63, w = tid >> 6;

    for (int idx = tid; idx < KTILES * 64; idx += 256) {
        int kt = idx >> 6, l = idx & 63;
        int ss = l & 15, k0 = kt * 32 + (l >> 4) * 8;
        uint4 o = make_uint4(0u, 0u, 0u, 0u), oa = o;
        if (ss < NS && k0 < DIN) {
            const float* src = ws + WS_Y2 + ss * DIN + k0;
            float4 a = *(const float4*)src, b = *(const float4*)(src + 4);
            o.x = pack2(a.x, a.y); o.y = pack2(a.z, a.w);
            o.z = pack2(b.x, b.y); o.w = pack2(b.z, b.w);
            oa.x = o.x & 0x7FFF7FFFu; oa.y = o.y & 0x7FFF7FFFu;
            oa.z = o.z & 0x7FFF7FFFu; oa.w = o.w & 0x7FFF7FFFu;
        }
        *(uint4*)(yf + (size_t)idx * 8) = o;
        *(uint4*)(ya + (size_t)idx * 8) = oa;
    }
    if (tid == 0) bsum = 0.f;
    __syncthreads();

    const int tile = blockIdx.x * 4 + w;       // 1024 tiles of 16 rows
    const int row  = tile * 16 + (lane & 15);
    const int kc   = lane >> 4;
    const int s    = lane & 15;
    const float* xp = x + (size_t)row * DIN;
    const float L001 = -6.90775527898f;        // ln(0.001f)

    f32x4 acc0 = (f32x4){0.f, 0.f, 0.f, 0.f};
    f32x4 acc1 = (f32x4){0.f, 0.f, 0.f, 0.f};
    float4 a0A, a1A, a0B, a1B;

    auto loadA = [&](int kt, float4& a0, float4& a1) {
        int k0 = kt * 32 + kc * 8;
        if (k0 + 8 > DIN) k0 = 768;
        a0 = *(const float4*)(xp + k0);
        a1 = *(const float4*)(xp + k0 + 4);
    };
    auto comp = [&](int kt, const float4& a0, const float4& a1) {
        bf16x8 nf; unsigned* p = (unsigned*)&nf;
        p[0] = pack2(1.f - 2.f * a0.x, 1.f - 2.f * a0.y);
        p[1] = pack2(1.f - 2.f * a0.z, 1.f - 2.f * a0.w);
        p[2] = pack2(1.f - 2.f * a1.x, 1.f - 2.f * a1.y);
        p[3] = pack2(1.f - 2.f * a1.z, 1.f - 2.f * a1.w);
        bf16x8 na; unsigned* q = (unsigned*)&na;
        q[0] = p[0] & 0x7FFF7FFFu; q[1] = p[1] & 0x7FFF7FFFu;
        q[2] = p[2] & 0x7FFF7FFFu; q[3] = p[3] & 0x7FFF7FFFu;
        bf16x8 fy = *(const bf16x8*)(yf + (size_t)kt * 512 + lane * 8);
        bf16x8 fa = *(const bf16x8*)(ya + (size_t)kt * 512 + lane * 8);
        acc0 = __builtin_amdgcn_mfma_f32_16x16x32_bf16(nf, fy, acc0, 0, 0, 0);
        acc1 = __builtin_amdgcn_mfma_f32_16x16x32_bf16(na, fa, acc1, 0, 0, 0);
    };

    loadA(0, a0A, a1A);
    for (int i = 0; i < 12; ++i) {
        loadA(2 * i + 1, a0B, a1B);
        comp(2 * i, a0A, a1A);
        loadA(2 * i + 2, a0A, a1A);
        comp(2 * i + 1, a0B, a1B);
    }
    comp(24, a0A, a1A);

    float bnd[4];
#pragma unroll
    for (int r = 0; r < 4; ++r) bnd[r] = 0.5f * (acc0[r] + acc1[r]);

    float wsum;
    bool lslow = (s < NS) &&
        (fminf(fminf(bnd[0], bnd[1]), fminf(bnd[2], bnd[3])) < BND_THR);
    unsigned long long m = __ballot(lslow);
    if (m == 0ull) {
        wsum = 160.f * L001;                   // 16 rows x 10 samples, all certified
    } else {
        int nslow = 0;
        float slowsum = 0.f;
#pragma unroll
        for (int r = 0; r < 4; ++r) {
            unsigned long long mr = __ballot((s < NS) && (bnd[r] < BND_THR));
            nslow += (int)__popcll(mr);
            while (mr) {
                int src = (int)__ffsll(mr) - 1; mr &= (mr - 1);
                int ss = src & 15;
                int rrow = tile * 16 + (src >> 4) * 4 + r;
                const float* xq = x + (size_t)rrow * DIN;
                const float* yq = ws + WS_Y2 + ss * DIN;
                float a = 0.f;
                for (int i = lane; i < DIN; i += 64)
                    a -= __builtin_amdgcn_logf(
                        1.f + __builtin_amdgcn_exp2f((1.f - 2.f * xq[i]) * yq[i]));
#pragma unroll
                for (int off = 32; off > 0; off >>= 1) a += __shfl_xor(a, off);
                slowsum += __logf(__builtin_amdgcn_exp2f(a) + 0.001f);
            }
        }
        wsum = (float)(160 - nslow) * L001 + slowsum;
    }
    if (lane == 0) atomicAdd(&bsum, wsum);
    __syncthreads();
    if (tid == 0) atomicAdd(out_sum, bsum);
}

// ---- final scalar ----
__global__ void final_kernel(const float* __restrict__ ws, float* __restrict__ out)
{
    float E = ws[200] * (1.f / ((float)NROWS * (float)NS));
    out[0] = -(E + ws[201]);
}

// ================= DIAGNOSTIC DISPATCHES (dead outputs, asm-sunk) =================

// R8-structure, staging+vmcnt+barriers only (no compute). Isolates the glds/L2 path.
__global__ __launch_bounds__(256, 4) void cm8_stageonly(
    const float* __restrict__ x, const ushort_t* __restrict__ Wb)
{
    __shared__ float    xs[2][2048];
    __shared__ ushort_t wt[2][2048];
    const int tid = threadIdx.x;
    int b = blockIdx.x;
    int logical = (b & 7) * 128 + (b >> 3);
    const int strip = logical >> 2, q = logical & 3;
    const int r0 = tid >> 3,         c0 = ((tid & 7) - r0) & 7;
    const int r1 = (tid + 256) >> 3, c1 = (((tid + 256) & 7) - r1) & 7;
    const float* xrow0 = x + (size_t)(strip * 64 + r0) * DIN;
    const float* xrow1 = x + (size_t)(strip * 64 + r1) * DIN;

    auto stage = [&](int kt, int buf) {
        int f0 = kt * 32 + c0 * 4; if (f0 + 4 > DIN) f0 = 0;
        int f1 = kt * 32 + c1 * 4; if (f1 + 4 > DIN) f1 = 0;
        glds16(xrow0 + f0, &xs[buf][tid * 4]);
        glds16(xrow1 + f1, &xs[buf][tid * 4 + 1024]);
        glds16u(Wb + (size_t)(kt * NCT + q * 4) * 512 + tid * 8, &wt[buf][tid * 8]);
    };

    stage(0, 0);
#pragma unroll 1
    for (int kt = 0; kt < KTILES; ++kt) {
        const int cur = kt & 1;
        if (kt + 1 < KTILES) {
            stage(kt + 1, cur ^ 1);
            asm volatile("s_waitcnt vmcnt(3)" ::: "memory");
        } else {
            asm volatile("s_waitcnt vmcnt(0)" ::: "memory");
        }
        __builtin_amdgcn_s_barrier();
        __builtin_amdgcn_sched_barrier(0);
        __builtin_amdgcn_s_barrier();
    }
    float t = xs[0][tid & 63] + xs[1][tid & 63]
            + (float)wt[0][tid & 63] + (float)wt[1][tid & 63];
    asm volatile("" :: "v"(t));
}

// R8-structure, barriers+LDS-read+MFMA only (stage once). Isolates barrier/compute.
__global__ __launch_bounds__(256, 4) void cm8_computeonly(
    const float* __restrict__ x, const ushort_t* __restrict__ Wb)
{
    __shared__ float    xs[2][2048];
    __shared__ ushort_t wt[2][2048];
    const int tid = threadIdx.x;
    const int lane = tid & 63, w = tid >> 6;
    int b = blockIdx.x;
    int logical = (b & 7) * 128 + (b >> 3);
    const int strip = logical >> 2, q = logical & 3;
    const int r0 = tid >> 3,         c0 = ((tid & 7) - r0) & 7;
    const int r1 = (tid + 256) >> 3, c1 = (((tid + 256) & 7) - r1) & 7;
    const float* xrow0 = x + (size_t)(strip * 64 + r0) * DIN;
    const float* xrow1 = x + (size_t)(strip * 64 + r1) * DIN;
    const int R  = w * 16 + (lane & 15);
    const int kc = lane >> 4;
    const int rsA = R * 32 + ((2 * kc + R) & 7) * 4;
    const int rsB = R * 32 + ((2 * kc + 1 + R) & 7) * 4;

    f32x4 acc[4];
#pragma unroll
    for (int jj = 0; jj < 4; ++jj) acc[jj] = (f32x4){0.f, 0.f, 0.f, 0.f};

    { // one-time stage
        glds16(xrow0 + c0 * 4, &xs[0][tid * 4]);
        glds16(xrow1 + c1 * 4, &xs[0][tid * 4 + 1024]);
        glds16u(Wb + (size_t)(q * 4) * 512 + tid * 8, &wt[0][tid * 8]);
        asm volatile("s_waitcnt vmcnt(0)" ::: "memory");
        __syncthreads();
    }
#pragma unroll 1
    for (int kt = 0; kt < KTILES; ++kt) {
        __builtin_amdgcn_s_barrier();
        asm volatile("" ::: "memory");         // force LDS re-read each step
        f32x4 xa = *(const f32x4*)(&xs[0][rsA]);
        f32x4 xb = *(const f32x4*)(&xs[0][rsB]);
        bf16x8 af; unsigned* p = (unsigned*)&af;
        p[0] = pack2(xa[0], xa[1]); p[1] = pack2(xa[2], xa[3]);
        p[2] = pack2(xb[0], xb[1]); p[3] = pack2(xb[2], xb[3]);
#pragma unroll
        for (int jj = 0; jj < 4; ++jj) {
            bf16x8 bf = *(const bf16x8*)(&wt[0][jj * 512 + lane * 8]);
            acc[jj] = __builtin_amdgcn_mfma_f32_16x16x32_bf16(af, bf, acc[jj], 0, 0, 0);
        }
        __builtin_amdgcn_sched_barrier(0);
        __builtin_amdgcn_s_barrier();
    }
    float t = 0.f;
#pragma unroll
    for (int jj = 0; jj < 4; ++jj)
#pragma unroll
        for (int r = 0; r < 4; ++r) t += acc[jj][r];
    asm volatile("" :: "v"(t));
}

// pure x stream: empirical read floor for 51.4 MB
__global__ __launch_bounds__(256) void xbw_kernel(const float* __restrict__ x)
{
    const int n4 = NROWS * DIN / 4;
    f32x4 s = (f32x4){0.f, 0.f, 0.f, 0.f};
    int stride = gridDim.x * 256;
    for (int i = blockIdx.x * 256 + threadIdx.x; i < n4; i += stride)
        s += *((const f32x4*)x + i);
    float t = s[0] + s[1] + s[2] + s[3];
    asm volatile("" :: "v"(t));
}

extern "C" void kernel_launch(void* const* d_in, const int* in_sizes, int n_in,
                              void* d_out, int out_size, void* d_ws, size_t ws_size,
                              hipStream_t stream)
{
    const float* x   = (const float*)d_in[0];
    const float* W0  = (const float*)d_in[1];
    const float* b0  = (const float*)d_in[2];
    const float* W1  = (const float*)d_in[3];
    const float* b1  = (const float*)d_in[4];
    const float* W2  = (const float*)d_in[5];
    const float* b2  = (const float*)d_in[6];
    const float* eps = (const float*)d_in[7];
    float* out = (float*)d_out;
    float* ws  = (float*)d_ws;
    ushort_t* Wb = (ushort_t*)(ws + WS_WB);

    hipMemsetAsync(ws, 0, 512 * sizeof(float), stream);
    wb2_kernel<<<(KT2 * NCT * 64 + 255) / 256, 256, 0, stream>>>(W0, W1, Wb);
    colmean_v2<<<2048, 256, 0, stream>>>(x, Wb, b0, b1, ws);
    middle_kernel<<<1, 256, 0, stream>>>(eps, ws);
    y2_kernel<<<(NS * DIN * 64) / 256, 256, 0, stream>>>(W2, b2, ws);
    pv_kernel<<<256, 256, 0, stream>>>(x, ws, ws + 200);
    final_kernel<<<1, 1, 0, stream>>>(ws, out);

    // diagnostics (dead outputs; removed next round)
    cm8_stageonly<<<1024, 256, 0, stream>>>(x, Wb);
    cm8_computeonly<<<1024, 256, 0, stream>>>(x, Wb);
    xbw_kernel<<<2048, 256, 0, stream>>>(x);
}

// Round 10
// 95.600 us; speedup vs baseline: 1.1239x; 1.1239x over previous
//
#include <hip/hip_runtime.h>
#include <hip/hip_bf16.h>
#include <math.h>

#define NROWS 16384
#define DIN   784
#define DZ    100
#define NS    10
#define NCT   16           // 16 col-tiles x 16 = 256 cols (200 real + 56 zero pad)
#define KTILES 25          // 25 * 32 = 800 >= 784
#define KT2   28           // Wb/yf padded to 28 kts so 4-way K-split runs 7 uniform steps
#define BND_THR 45.0f

typedef unsigned short ushort_t;
typedef short bf16x8 __attribute__((ext_vector_type(8)));
typedef float f32x4  __attribute__((ext_vector_type(4)));

// ws layout:
//  floats [0..199] colsum softplus (atomic)  [200] pv log-sum  [201] Dkl
//  floats [208..8047] y2[s][i] = y*log2e     [8064..9063] z[s][d]
//  byte 64KB..: Wb bf16 frag-swizzled W, 28*16*512 ushorts (448 KB)
//  byte 1MB..:  Xf bf16 A-frags of x, 1024*25*512 ushorts (26.2 MB) [if ws fits]
#define WS_Y2 208
#define WS_Z  8064
#define WB_OFF_BYTES  (64u * 1024u)
#define XF_OFF_BYTES  (1024u * 1024u)
#define XF_BYTES      ((size_t)1024 * KTILES * 512 * 2)
#define WS_NEED_BYTES (XF_OFF_BYTES + XF_BYTES)

__device__ __forceinline__ float softplusf(float v) {
    return fmaxf(v, 0.f) + log1pf(__expf(-fabsf(v)));
}
__device__ __forceinline__ unsigned pack2(float lo, float hi) {
    float2 f2; f2.x = lo; f2.y = hi;
    __hip_bfloat162 h2 = __float22bfloat162_rn(f2);
    return *reinterpret_cast<unsigned*>(&h2);
}

// ---- W -> bf16, MFMA B-fragment order, kt padded to 28 ----
__global__ __launch_bounds__(256) void wb2_kernel(
    const float* __restrict__ W0, const float* __restrict__ W1, ushort_t* __restrict__ Wb)
{
    int t = blockIdx.x * 256 + threadIdx.x;
    if (t >= KT2 * NCT * 64) return;
    int kt = t >> 10;
    int r  = t & 1023;
    int ct = r >> 6, l = r & 63;
    int col = ct * 16 + (l & 15);
    int k0  = kt * 32 + (l >> 4) * 8;
    uint4 o = make_uint4(0u, 0u, 0u, 0u);
    if (col < 200 && k0 < DIN) {
        const float* src = (col < 100 ? W0 + (size_t)col * DIN
                                      : W1 + (size_t)(col - 100) * DIN) + k0;
        float4 a = *(const float4*)src;
        float4 b = *(const float4*)(src + 4);
        o.x = pack2(a.x, a.y); o.y = pack2(a.z, a.w);
        o.z = pack2(b.x, b.y); o.w = pack2(b.z, b.w);
    }
    *(uint4*)(Wb + (size_t)t * 8) = o;
}

// ---- x -> bf16 A-fragments (coalesced read, scattered 16B write) ----
// Xf[((rt*25 + kt)*64 + lane)*8 + j] = bf16(x[rt*16 + (lane&15)][kt*32 + (lane>>4)*8 + j])
__global__ __launch_bounds__(256) void xfrag_kernel(
    const float* __restrict__ x, ushort_t* __restrict__ Xf)
{
    int t = blockIdx.x * 256 + threadIdx.x;   // t = r*100 + kt*4 + kc
    if (t >= NROWS * 100) return;
    int r  = t / 100;
    int sl = t - r * 100;
    int kt = sl >> 2, kc = sl & 3;
    int k0 = kt * 32 + kc * 8;
    uint4 o = make_uint4(0u, 0u, 0u, 0u);
    if (k0 + 8 <= DIN) {
        const float* src = x + (size_t)r * DIN + k0;
        float4 a = *(const float4*)src;
        float4 b = *(const float4*)(src + 4);
        o.x = pack2(a.x, a.y); o.y = pack2(a.z, a.w);
        o.z = pack2(b.x, b.y); o.w = pack2(b.z, b.w);
    }
    int lane = (kc << 4) | (r & 15);
    *(uint4*)(Xf + ((size_t)((r >> 4) * KTILES + kt) * 64 + lane) * 8) = o;
}

// ---- colmean v3: frag-linear GEMM, no barriers in K-loop ----
// 1024 blocks x 4 waves. Block = 32 rows (2 frag row-tiles) x 8 col-tiles (half).
// Waves K-split: kt = w, w+4, ..., w+24 (7 steps). A from Xf (clamp kt>24 -> junk,
// B zero there). Named reg dbuf; ample VGPR headroom so it can't collapse.
#define RED(ws_, l_, c_) red[(((ws_) * 64) + (l_)) * 65 + (c_)]
__global__ __launch_bounds__(256, 2) void colmean_v3(
    const ushort_t* __restrict__ Xf, const ushort_t* __restrict__ Wb,
    const float* __restrict__ b0, const float* __restrict__ b1,
    float* __restrict__ ws)
{
    __shared__ float red[2 * 64 * 65];     // 33.3 KB
    const int tid = threadIdx.x;
    const int lane = tid & 63, w = tid >> 6;

    int b = blockIdx.x;                    // XCD-bijective: 1024 = 8 * 128
    int logical = (b & 7) * 128 + (b >> 3);
    const int rowchunk = logical >> 1, half = logical & 1;

    const ushort_t* xf0 = Xf + (size_t)(rowchunk * 2)     * KTILES * 512 + lane * 8;
    const ushort_t* xf1 = Xf + (size_t)(rowchunk * 2 + 1) * KTILES * 512 + lane * 8;

    f32x4 acc[2][8];
#pragma unroll
    for (int rg = 0; rg < 2; ++rg)
#pragma unroll
        for (int jj = 0; jj < 8; ++jj) acc[rg][jj] = (f32x4){0.f, 0.f, 0.f, 0.f};

    uint4 A0a, A1a, A0b, A1b;
    uint4 Ba[8], Bb[8];

    auto loadA = [&](int kt, uint4& A0, uint4& A1) {
        int ktc = (kt <= 24) ? kt : 0;     // junk ok: Wb zero at kt>=25
        A0 = *(const uint4*)(xf0 + ktc * 512);
        A1 = *(const uint4*)(xf1 + ktc * 512);
    };
    auto loadB = [&](int kt, uint4 (&B)[8]) {
#pragma unroll
        for (int jj = 0; jj < 8; ++jj)
            B[jj] = *(const uint4*)(Wb + ((size_t)(kt * NCT + half * 8 + jj) * 64 + lane) * 8);
    };
    auto comp = [&](const uint4& A0, const uint4& A1, const uint4 (&B)[8]) {
        bf16x8 af0 = *(const bf16x8*)&A0;
        bf16x8 af1 = *(const bf16x8*)&A1;
#pragma unroll
        for (int jj = 0; jj < 8; ++jj) {
            bf16x8 bf = *(const bf16x8*)&B[jj];
            acc[0][jj] = __builtin_amdgcn_mfma_f32_16x16x32_bf16(af0, bf, acc[0][jj], 0, 0, 0);
            acc[1][jj] = __builtin_amdgcn_mfma_f32_16x16x32_bf16(af1, bf, acc[1][jj], 0, 0, 0);
        }
    };

    loadA(w, A0a, A1a); loadB(w, Ba);
#pragma unroll
    for (int i = 0; i < 3; ++i) {
        loadA(w + 4 * (2 * i + 1), A0b, A1b); loadB(w + 4 * (2 * i + 1), Bb);
        __builtin_amdgcn_sched_barrier(0);
        comp(A0a, A1a, Ba);
        loadA(w + 4 * (2 * i + 2), A0a, A1a); loadB(w + 4 * (2 * i + 2), Ba);
        __builtin_amdgcn_sched_barrier(0);
        comp(A0b, A1b, Bb);
    }
    comp(A0a, A1a, Ba);                    // kt = w + 24

    // cross-wave K reduce (stride-65 LDS, conflict-free)
    if (w >= 2) {
#pragma unroll
        for (int rg = 0; rg < 2; ++rg)
#pragma unroll
            for (int jj = 0; jj < 8; ++jj)
#pragma unroll
                for (int r = 0; r < 4; ++r)
                    RED(w - 2, lane, rg * 32 + jj * 4 + r) = acc[rg][jj][r];
    }
    __syncthreads();
    if (w < 2) {
#pragma unroll
        for (int rg = 0; rg < 2; ++rg)
#pragma unroll
            for (int jj = 0; jj < 8; ++jj)
#pragma unroll
                for (int r = 0; r < 4; ++r)
                    acc[rg][jj][r] += RED(w, lane, rg * 32 + jj * 4 + r);
    }
    __syncthreads();
    if (w == 1) {
#pragma unroll
        for (int rg = 0; rg < 2; ++rg)
#pragma unroll
            for (int jj = 0; jj < 8; ++jj)
#pragma unroll
                for (int r = 0; r < 4; ++r)
                    RED(0, lane, rg * 32 + jj * 4 + r) = acc[rg][jj][r];
    }
    __syncthreads();
    if (w == 0) {
#pragma unroll
        for (int jj = 0; jj < 8; ++jj) {
            int j = (half * 8 + jj) * 16 + (lane & 15);
            float bias = (j < 100) ? b0[j] : ((j < 200) ? b1[j - 100] : 0.f);
            float v = 0.f;
#pragma unroll
            for (int rg = 0; rg < 2; ++rg)
#pragma unroll
                for (int r = 0; r < 4; ++r)
                    v += softplusf(acc[rg][jj][r] + RED(0, lane, rg * 32 + jj * 4 + r) + bias);
            v += __shfl_xor(v, 16);
            v += __shfl_xor(v, 32);
            if ((lane >> 4) == 0 && j < 200) atomicAdd(&ws[j], v);
        }
    }
}

// ---- colmean v2 (R9): fallback when ws too small for Xf ----
#define RED2(ws_, l_, c_) red[(((ws_) * 64) + (l_)) * 33 + (c_)]
__global__ __launch_bounds__(256, 4) void colmean_v2(
    const float* __restrict__ x, const ushort_t* __restrict__ Wb,
    const float* __restrict__ b0, const float* __restrict__ b1,
    float* __restrict__ ws)
{
    __shared__ float red[2 * 64 * 33];
    const int tid = threadIdx.x;
    const int lane = tid & 63, w = tid >> 6;
    int b = blockIdx.x;
    int logical = (b & 7) * 256 + (b >> 3);
    const int strip = logical >> 2, q = logical & 3;
    const float* xr0 = x + (size_t)(strip * 32 + (lane & 15)) * DIN;
    const float* xr1 = xr0 + (size_t)16 * DIN;
    const int kc = lane >> 4;

    f32x4 acc[2][4];
#pragma unroll
    for (int rg = 0; rg < 2; ++rg)
#pragma unroll
        for (int jj = 0; jj < 4; ++jj) acc[rg][jj] = (f32x4){0.f, 0.f, 0.f, 0.f};

    float4 Aa[4], Ab[4];
    uint4  Ba[4], Bb[4];
    auto loadA = [&](int kt, float4 (&A)[4]) {
        int k0 = kt * 32 + kc * 8;
        if (k0 + 8 > DIN) k0 = 768;
        A[0] = *(const float4*)(xr0 + k0);
        A[1] = *(const float4*)(xr0 + k0 + 4);
        A[2] = *(const float4*)(xr1 + k0);
        A[3] = *(const float4*)(xr1 + k0 + 4);
    };
    auto loadB = [&](int kt, uint4 (&B)[4]) {
#pragma unroll
        for (int jj = 0; jj < 4; ++jj)
            B[jj] = *(const uint4*)(Wb + ((size_t)((kt * NCT + q * 4 + jj) * 64 + lane)) * 8);
    };
    auto comp = [&](const float4 (&A)[4], const uint4 (&B)[4]) {
#pragma unroll
        for (int rg = 0; rg < 2; ++rg) {
            bf16x8 af; unsigned* p = (unsigned*)&af;
            p[0] = pack2(A[2 * rg].x, A[2 * rg].y);
            p[1] = pack2(A[2 * rg].z, A[2 * rg].w);
            p[2] = pack2(A[2 * rg + 1].x, A[2 * rg + 1].y);
            p[3] = pack2(A[2 * rg + 1].z, A[2 * rg + 1].w);
#pragma unroll
            for (int jj = 0; jj < 4; ++jj)
                acc[rg][jj] = __builtin_amdgcn_mfma_f32_16x16x32_bf16(
                    af, *(const bf16x8*)&B[jj], acc[rg][jj], 0, 0, 0);
        }
    };
    loadA(w, Aa); loadB(w, Ba);
#pragma unroll
    for (int i = 0; i < 3; ++i) {
        loadA(w + 4 * (2 * i + 1), Ab); loadB(w + 4 * (2 * i + 1), Bb);
        __builtin_amdgcn_sched_barrier(0);
        comp(Aa, Ba);
        loadA(w + 4 * (2 * i + 2), Aa); loadB(w + 4 * (2 * i + 2), Ba);
        __builtin_amdgcn_sched_barrier(0);
        comp(Ab, Bb);
    }
    comp(Aa, Ba);
    if (w >= 2) {
#pragma unroll
        for (int rg = 0; rg < 2; ++rg)
#pragma unroll
            for (int jj = 0; jj < 4; ++jj)
#pragma unroll
                for (int r = 0; r < 4; ++r)
                    RED2(w - 2, lane, rg * 16 + jj * 4 + r) = acc[rg][jj][r];
    }
    __syncthreads();
    if (w < 2) {
#pragma unroll
        for (int rg = 0; rg < 2; ++rg)
#pragma unroll
            for (int jj = 0; jj < 4; ++jj)
#pragma unroll
                for (int r = 0; r < 4; ++r)
                    acc[rg][jj][r] += RED2(w, lane, rg * 16 + jj * 4 + r);
    }
    __syncthreads();
    if (w == 1) {
#pragma unroll
        for (int rg = 0; rg < 2; ++rg)
#pragma unroll
            for (int jj = 0; jj < 4; ++jj)
#pragma unroll
                for (int r = 0; r < 4; ++r)
                    RED2(0, lane, rg * 16 + jj * 4 + r) = acc[rg][jj][r];
    }
    __syncthreads();
    if (w == 0) {
#pragma unroll
        for (int jj = 0; jj < 4; ++jj) {
            int j = (q * 4 + jj) * 16 + (lane & 15);
            float bias = (j < 100) ? b0[j] : ((j < 200) ? b1[j - 100] : 0.f);
            float v = 0.f;
#pragma unroll
            for (int rg = 0; rg < 2; ++rg)
#pragma unroll
                for (int r = 0; r < 4; ++r)
                    v += softplusf(acc[rg][jj][r] + RED2(0, lane, rg * 16 + jj * 4 + r) + bias);
            v += __shfl_xor(v, 16);
            v += __shfl_xor(v, 32);
            if ((lane >> 4) == 0 && j < 200) atomicAdd(&ws[j], v);
        }
    }
}

// ---- mean/cov, z, Dkl ----
__global__ __launch_bounds__(256) void middle_kernel(
    const float* __restrict__ eps, float* __restrict__ ws)
{
    __shared__ float red[256];
    const int tid = threadIdx.x;
    float contrib = 0.f;
    if (tid < DZ) {
        const float inv = 1.f / (float)NROWS;
        float mm = ws[tid] * inv;
        float cc = ws[100 + tid] * inv;
        contrib = 0.5f * __logf(cc);
#pragma unroll
        for (int s = 0; s < NS; ++s) {
            float e = eps[s * DZ + tid];
            float zz = mm + cc * e;
            ws[WS_Z + s * DZ + tid] = zz;
            contrib += (0.5f * cc * e * e - 0.5f * zz * zz) * (1.f / NS);
        }
    }
    red[tid] = contrib;
    __syncthreads();
    for (int off = 128; off > 0; off >>= 1) {
        if (tid < off) red[tid] += red[tid + off];
        __syncthreads();
    }
    if (tid == 0) ws[201] = red[0];
}

// ---- y2 = (z @ W2.T + b2) * log2e ----
__global__ __launch_bounds__(256) void y2_kernel(
    const float* __restrict__ W2, const float* __restrict__ b2,
    float* __restrict__ ws)
{
    int wid  = (int)((blockIdx.x * 256 + threadIdx.x) >> 6);
    int lane = threadIdx.x & 63;
    if (wid >= NS * DIN) return;
    int s = wid / DIN, i = wid % DIN;
    const float* zz = ws + WS_Z + s * DZ;
    const float* wr = W2 + (size_t)i * DZ;
    float p = 0.f;
    for (int d = lane; d < DZ; d += 64) p += zz[d] * wr[d];
#pragma unroll
    for (int off = 32; off > 0; off >>= 1) p += __shfl_xor(p, off);
    if (lane == 0) ws[WS_Y2 + wid] = (p + b2[i]) * 1.4426950408889634f;
}

// ---- pv v3: frag-linear bound GEMM ----
// 1024 blocks x 4 waves; block = one 16-row tile; waves K-split (7 steps).
// A-frag from Xf -> u = 1-2x repacked in-reg; B = y-frags in LDS (28 kt, zero-padded).
__global__ __launch_bounds__(256, 4) void pv_v3(
    const float* __restrict__ x, const float* ws,
    const ushort_t* __restrict__ Xf, float* out_sum)
{
    __shared__ ushort_t yf[KT2 * 512];     // 28.7 KB
    __shared__ float red[4 * 64 * 9];      // 9.2 KB
    const int tid = threadIdx.x;
    const int lane = tid & 63, w = tid >> 6;

    for (int idx = tid; idx < KT2 * 64; idx += 256) {
        int kt = idx >> 6, l = idx & 63;
        int ss = l & 15, k0 = kt * 32 + (l >> 4) * 8;
        uint4 o = make_uint4(0u, 0u, 0u, 0u);
        if (ss < NS && k0 + 8 <= DIN) {
            const float* src = ws + WS_Y2 + (size_t)ss * DIN + k0;
            float4 a = *(const float4*)src, b2v = *(const float4*)(src + 4);
            o.x = pack2(a.x, a.y); o.y = pack2(a.z, a.w);
            o.z = pack2(b2v.x, b2v.y); o.w = pack2(b2v.z, b2v.w);
        }
        *(uint4*)(yf + (size_t)idx * 8) = o;
    }
    __syncthreads();

    int b = blockIdx.x;                    // XCD-bijective: 1024 = 8 * 128
    const int tile = (b & 7) * 128 + (b >> 3);
    const ushort_t* xf = Xf + (size_t)tile * KTILES * 512 + lane * 8;
    const float L001 = -6.90775527898f;    // ln(0.001f)

    f32x4 acc0 = (f32x4){0.f, 0.f, 0.f, 0.f};
    f32x4 acc1 = (f32x4){0.f, 0.f, 0.f, 0.f};

    auto ustep = [&](int kt, const uint4& X) {
        bf16x8 nf; unsigned* p = (unsigned*)&nf;
        const unsigned* xw = (const unsigned*)&X;
#pragma unroll
        for (int i2 = 0; i2 < 4; ++i2) {
            float lo = __uint_as_float(xw[i2] << 16);
            float hi = __uint_as_float(xw[i2] & 0xFFFF0000u);
            p[i2] = pack2(1.f - 2.f * lo, 1.f - 2.f * hi);
        }
        bf16x8 na; unsigned* q = (unsigned*)&na;
        q[0] = p[0] & 0x7FFF7FFFu; q[1] = p[1] & 0x7FFF7FFFu;
        q[2] = p[2] & 0x7FFF7FFFu; q[3] = p[3] & 0x7FFF7FFFu;
        bf16x8 fy = *(const bf16x8*)(yf + (size_t)kt * 512 + lane * 8);
        bf16x8 fa; unsigned* fq = (unsigned*)&fa; const unsigned* fp = (const unsigned*)&fy;
        fq[0] = fp[0] & 0x7FFF7FFFu; fq[1] = fp[1] & 0x7FFF7FFFu;
        fq[2] = fp[2] & 0x7FFF7FFFu; fq[3] = fp[3] & 0x7FFF7FFFu;
        acc0 = __builtin_amdgcn_mfma_f32_16x16x32_bf16(nf, fy, acc0, 0, 0, 0);
        acc1 = __builtin_amdgcn_mfma_f32_16x16x32_bf16(na, fa, acc1, 0, 0, 0);
    };
    auto loadX = [&](int kt, uint4& X) {
        int ktc = (kt <= 24) ? kt : 0;     // junk ok: yf zero at kt>=25
        X = *(const uint4*)(xf + ktc * 512);
    };

    uint4 Xa, Xb;
    loadX(w, Xa);
#pragma unroll
    for (int i = 0; i < 3; ++i) {
        loadX(w + 4 * (2 * i + 1), Xb);
        __builtin_amdgcn_sched_barrier(0);
        ustep(w + 4 * (2 * i), Xa);
        loadX(w + 4 * (2 * i + 2), Xa);
        __builtin_amdgcn_sched_barrier(0);
        ustep(w + 4 * (2 * i + 1), Xb);
    }
    ustep(w + 24, Xa);

#pragma unroll
    for (int r = 0; r < 4; ++r) {
        red[(w * 64 + lane) * 9 + r]     = acc0[r];
        red[(w * 64 + lane) * 9 + 4 + r] = acc1[r];
    }
    __syncthreads();

    if (w == 0) {
        const int s = lane & 15;
        float bnd[4];
#pragma unroll
        for (int r = 0; r < 4; ++r) {
            float s0 = 0.f, s1 = 0.f;
#pragma unroll
            for (int ww = 0; ww < 4; ++ww) {
                s0 += red[(ww * 64 + lane) * 9 + r];
                s1 += red[(ww * 64 + lane) * 9 + 4 + r];
            }
            bnd[r] = 0.5f * (s0 + s1);
        }
        float wsum;
        bool lslow = (s < NS) &&
            (fminf(fminf(bnd[0], bnd[1]), fminf(bnd[2], bnd[3])) < BND_THR);
        unsigned long long m = __ballot(lslow);
        if (m == 0ull) {
            wsum = 160.f * L001;
        } else {
            int nslow = 0;
            float slowsum = 0.f;
#pragma unroll
            for (int r = 0; r < 4; ++r) {
                unsigned long long mr = __ballot((s < NS) && (bnd[r] < BND_THR));
                nslow += (int)__popcll(mr);
                while (mr) {
                    int src = (int)__ffsll(mr) - 1; mr &= (mr - 1);
                    int ss = src & 15;
                    int rrow = tile * 16 + (src >> 4) * 4 + r;
                    const float* xq = x + (size_t)rrow * DIN;
                    const float* yq = ws + WS_Y2 + (size_t)ss * DIN;
                    float a = 0.f;
                    for (int i = lane; i < DIN; i += 64)
                        a -= __builtin_amdgcn_logf(
                            1.f + __builtin_amdgcn_exp2f((1.f - 2.f * xq[i]) * yq[i]));
#pragma unroll
                    for (int off = 32; off > 0; off >>= 1) a += __shfl_xor(a, off);
                    slowsum += __logf(__builtin_amdgcn_exp2f(a) + 0.001f);
                }
            }
            wsum = (float)(160 - nslow) * L001 + slowsum;
        }
        if (lane == 0) atomicAdd(out_sum, wsum);
    }
}

// ---- pv fallback (R5 version): used when ws too small for Xf ----
__global__ __launch_bounds__(256, 4) void pv_old(
    const float* __restrict__ x, const float* ws, float* out_sum)
{
    __shared__ ushort_t yf[KTILES * 512];
    __shared__ ushort_t ya[KTILES * 512];
    __shared__ float bsum;
    const int tid = threadIdx.x;
    const int lane = tid & 63, w = tid >> 6;

    for (int idx = tid; idx < KTILES * 64; idx += 256) {
        int kt = idx >> 6, l = idx & 63;
        int ss = l & 15, k0 = kt * 32 + (l >> 4) * 8;
        uint4 o = make_uint4(0u, 0u, 0u, 0u), oa = o;
        if (ss < NS && k0 < DIN) {
            const float* src = ws + WS_Y2 + ss * DIN + k0;
            float4 a = *(const float4*)src, b = *(const float4*)(src + 4);
            o.x = pack2(a.x, a.y); o.y = pack2(a.z, a.w);
            o.z = pack2(b.x, b.y); o.w = pack2(b.z, b.w);
            oa.x = o.x & 0x7FFF7FFFu; oa.y = o.y & 0x7FFF7FFFu;
            oa.z = o.z & 0x7FFF7FFFu; oa.w = o.w & 0x7FFF7FFFu;
        }
        *(uint4*)(yf + (size_t)idx * 8) = o;
        *(uint4*)(ya + (size_t)idx * 8) = oa;
    }
    if (tid == 0) bsum = 0.f;
    __syncthreads();

    const int tile = blockIdx.x * 4 + w;
    const int row  = tile * 16 + (lane & 15);
    const int kc   = lane >> 4;
    const int s    = lane & 15;
    const float* xp = x + (size_t)row * DIN;
    const float L001 = -6.90775527898f;

    f32x4 acc0 = (f32x4){0.f, 0.f, 0.f, 0.f};
    f32x4 acc1 = (f32x4){0.f, 0.f, 0.f, 0.f};
    float4 a0A, a1A, a0B, a1B;

    auto loadA = [&](int kt, float4& a0, float4& a1) {
        int k0 = kt * 32 + kc * 8;
        if (k0 + 8 > DIN) k0 = 768;
        a0 = *(const float4*)(xp + k0);
        a1 = *(const float4*)(xp + k0 + 4);
    };
    auto comp = [&](int kt, const float4& a0, const float4& a1) {
        bf16x8 nf; unsigned* p = (unsigned*)&nf;
        p[0] = pack2(1.f - 2.f * a0.x, 1.f - 2.f * a0.y);
        p[1] = pack2(1.f - 2.f * a0.z, 1.f - 2.f * a0.w);
        p[2] = pack2(1.f - 2.f * a1.x, 1.f - 2.f * a1.y);
        p[3] = pack2(1.f - 2.f * a1.z, 1.f - 2.f * a1.w);
        bf16x8 na; unsigned* q = (unsigned*)&na;
        q[0] = p[0] & 0x7FFF7FFFu; q[1] = p[1] & 0x7FFF7FFFu;
        q[2] = p[2] & 0x7FFF7FFFu; q[3] = p[3] & 0x7FFF7FFFu;
        bf16x8 fy = *(const bf16x8*)(yf + (size_t)kt * 512 + lane * 8);
        bf16x8 fa = *(const bf16x8*)(ya + (size_t)kt * 512 + lane * 8);
        acc0 = __builtin_amdgcn_mfma_f32_16x16x32_bf16(nf, fy, acc0, 0, 0, 0);
        acc1 = __builtin_amdgcn_mfma_f32_16x16x32_bf16(na, fa, acc1, 0, 0, 0);
    };
    loadA(0, a0A, a1A);
    for (int i = 0; i < 12; ++i) {
        loadA(2 * i + 1, a0B, a1B);
        comp(2 * i, a0A, a1A);
        loadA(2 * i + 2, a0A, a1A);
        comp(2 * i + 1, a0B, a1B);
    }
    comp(24, a0A, a1A);

    float bnd[4];
#pragma unroll
    for (int r = 0; r < 4; ++r) bnd[r] = 0.5f * (acc0[r] + acc1[r]);
    float wsum;
    bool lslow = (s < NS) &&
        (fminf(fminf(bnd[0], bnd[1]), fminf(bnd[2], bnd[3])) < BND_THR);
    unsigned long long m = __ballot(lslow);
    if (m == 0ull) {
        wsum = 160.f * L001;
    } else {
        int nslow = 0;
        float slowsum = 0.f;
#pragma unroll
        for (int r = 0; r < 4; ++r) {
            unsigned long long mr = __ballot((s < NS) && (bnd[r] < BND_THR));
            nslow += (int)__popcll(mr);
            while (mr) {
                int src = (int)__ffsll(mr) - 1; mr &= (mr - 1);
                int ss = src & 15;
                int rrow = tile * 16 + (src >> 4) * 4 + r;
                const float* xq = x + (size_t)rrow * DIN;
                const float* yq = ws + WS_Y2 + ss * DIN;
                float a = 0.f;
                for (int i = lane; i < DIN; i += 64)
                    a -= __builtin_amdgcn_logf(
                        1.f + __builtin_amdgcn_exp2f((1.f - 2.f * xq[i]) * yq[i]));
#pragma unroll
                for (int off = 32; off > 0; off >>= 1) a += __shfl_xor(a, off);
                slowsum += __logf(__builtin_amdgcn_exp2f(a) + 0.001f);
            }
        }
        wsum = (float)(160 - nslow) * L001 + slowsum;
    }
    if (lane == 0) atomicAdd(&bsum, wsum);
    __syncthreads();
    if (tid == 0) atomicAdd(out_sum, bsum);
}

// ---- final scalar ----
__global__ void final_kernel(const float* __restrict__ ws, float* __restrict__ out)
{
    float E = ws[200] * (1.f / ((float)NROWS * (float)NS));
    out[0] = -(E + ws[201]);
}

extern "C" void kernel_launch(void* const* d_in, const int* in_sizes, int n_in,
                              void* d_out, int out_size, void* d_ws, size_t ws_size,
                              hipStream_t stream)
{
    const float* x   = (const float*)d_in[0];
    const float* W0  = (const float*)d_in[1];
    const float* b0  = (const float*)d_in[2];
    const float* W1  = (const float*)d_in[3];
    const float* b1  = (const float*)d_in[4];
    const float* W2  = (const float*)d_in[5];
    const float* b2  = (const float*)d_in[6];
    const float* eps = (const float*)d_in[7];
    float* out = (float*)d_out;
    float* ws  = (float*)d_ws;
    ushort_t* Wb = (ushort_t*)((char*)d_ws + WB_OFF_BYTES);
    ushort_t* Xf = (ushort_t*)((char*)d_ws + XF_OFF_BYTES);

    hipMemsetAsync(ws, 0, 512 * sizeof(float), stream);
    wb2_kernel<<<(KT2 * NCT * 64 + 255) / 256, 256, 0, stream>>>(W0, W1, Wb);

    if (ws_size >= WS_NEED_BYTES) {
        xfrag_kernel<<<(NROWS * 100 + 255) / 256, 256, 0, stream>>>(x, Xf);
        colmean_v3<<<1024, 256, 0, stream>>>(Xf, Wb, b0, b1, ws);
        middle_kernel<<<1, 256, 0, stream>>>(eps, ws);
        y2_kernel<<<(NS * DIN * 64) / 256, 256, 0, stream>>>(W2, b2, ws);
        pv_v3<<<1024, 256, 0, stream>>>(x, ws, Xf, ws + 200);
    } else {
        colmean_v2<<<2048, 256, 0, stream>>>(x, Wb, b0, b1, ws);
        middle_kernel<<<1, 256, 0, stream>>>(eps, ws);
        y2_kernel<<<(NS * DIN * 64) / 256, 256, 0, stream>>>(W2, b2, ws);
        pv_old<<<256, 256, 0, stream>>>(x, ws, ws + 200);
    }
    final_kernel<<<1, 1, 0, stream>>>(ws, out);
}

// Round 11
// 83.510 us; speedup vs baseline: 1.2866x; 1.1448x over previous
//
#include <hip/hip_runtime.h>
#include <hip/hip_bf16.h>
#include <math.h>

#define NROWS 16384
#define DIN   784
#define DZ    100
#define NS    10
#define NCT   16           // 16 col-tiles x 16 = 256 cols (200 real + 56 zero pad)
#define KTILES 25          // 25 * 32 = 800 >= 784
#define KT2   28           // Wb padded to 28 kts (fallback colmean_v2 needs it)
#define BND_THR 45.0f

typedef unsigned short ushort_t;
typedef short bf16x8 __attribute__((ext_vector_type(8)));
typedef float f32x4  __attribute__((ext_vector_type(4)));

// ws layout:
//  floats [0..199] colsum softplus (atomic)  [200] pv log-sum  [201] Dkl
//  floats [208..8047] y2[s][i] = y*log2e     [8064..9063] z[s][d]
//  byte 64KB..: Wb bf16 frag-swizzled W, 28*16*512 ushorts (448 KB)
//  byte 1MB..:  Xf bf16 A-frags of x, 1024*25*512 ushorts (26.2 MB) [if ws fits]
#define WS_Y2 208
#define WS_Z  8064
#define WB_OFF_BYTES  (64u * 1024u)
#define XF_OFF_BYTES  (1024u * 1024u)
#define XF_BYTES      ((size_t)1024 * KTILES * 512 * 2)
#define WS_NEED_BYTES (XF_OFF_BYTES + XF_BYTES)
#define WB_BLOCKS 112      // (KT2*NCT*64)/256
#define XF_BLOCKS 6400     // (NROWS*100)/256

__device__ __forceinline__ float softplusf(float v) {   // libm version (fallback kernels)
    return fmaxf(v, 0.f) + log1pf(__expf(-fabsf(v)));
}
__device__ __forceinline__ float softplus_fast(float v) {
    // ln(1+e^v) = (max(t,0) + log2(1+2^-|t|)) * ln2, t = v*log2e  (v_exp/v_log pipes)
    float t = v * 1.44269504088896f;
    return (fmaxf(t, 0.f)
            + __builtin_amdgcn_logf(1.f + __builtin_amdgcn_exp2f(-fabsf(t))))
           * 0.69314718055995f;
}
__device__ __forceinline__ unsigned pack2(float lo, float hi) {
    float2 f2; f2.x = lo; f2.y = hi;
    __hip_bfloat162 h2 = __float22bfloat162_rn(f2);
    return *reinterpret_cast<unsigned*>(&h2);
}

// ---- prep: Wb (W -> bf16 B-frags, kt padded) + Xf (x -> bf16 A-frags) fused ----
__global__ __launch_bounds__(256) void prep_kernel(
    const float* __restrict__ W0, const float* __restrict__ W1,
    const float* __restrict__ x,
    ushort_t* __restrict__ Wb, ushort_t* __restrict__ Xf, int do_xf)
{
    int bb = blockIdx.x;
    if (bb < WB_BLOCKS) {
        int t = bb * 256 + threadIdx.x;
        if (t >= KT2 * NCT * 64) return;
        int kt = t >> 10;
        int r  = t & 1023;
        int ct = r >> 6, l = r & 63;
        int col = ct * 16 + (l & 15);
        int k0  = kt * 32 + (l >> 4) * 8;
        uint4 o = make_uint4(0u, 0u, 0u, 0u);
        if (col < 200 && k0 < DIN) {
            const float* src = (col < 100 ? W0 + (size_t)col * DIN
                                          : W1 + (size_t)(col - 100) * DIN) + k0;
            float4 a = *(const float4*)src;
            float4 b = *(const float4*)(src + 4);
            o.x = pack2(a.x, a.y); o.y = pack2(a.z, a.w);
            o.z = pack2(b.x, b.y); o.w = pack2(b.z, b.w);
        }
        *(uint4*)(Wb + (size_t)t * 8) = o;
    } else if (do_xf) {
        int t = (bb - WB_BLOCKS) * 256 + threadIdx.x;   // t = r*100 + kt*4 + kc
        if (t >= NROWS * 100) return;
        int r  = t / 100;
        int sl = t - r * 100;
        int kt = sl >> 2, kc = sl & 3;
        int k0 = kt * 32 + kc * 8;
        uint4 o = make_uint4(0u, 0u, 0u, 0u);
        if (k0 + 8 <= DIN) {
            const float* src = x + (size_t)r * DIN + k0;
            float4 a = *(const float4*)src;
            float4 b = *(const float4*)(src + 4);
            o.x = pack2(a.x, a.y); o.y = pack2(a.z, a.w);
            o.z = pack2(b.x, b.y); o.w = pack2(b.z, b.w);
        }
        int lane = (kc << 4) | (r & 15);
        *(uint4*)(Xf + ((size_t)((r >> 4) * KTILES + kt) * 64 + lane) * 8) = o;
    }
}

// ---- colmean v4: full-K per wave, ZERO LDS, ZERO barriers, no sched pins ----
// 1024 blocks x 4 waves. Block = 32 rows x 8 col-tiles (half). Wave w: both
// rowtiles x col-tiles {half*8+2w, +1}. Per step: 4 coalesced uint4 loads + 4 MFMA.
__global__ __launch_bounds__(256) void colmean_v4(
    const ushort_t* __restrict__ Xf, const ushort_t* __restrict__ Wb,
    const float* __restrict__ b0, const float* __restrict__ b1,
    float* __restrict__ ws)
{
    const int tid = threadIdx.x;
    const int lane = tid & 63, w = tid >> 6;

    int b = blockIdx.x;                    // XCD-bijective: 1024 = 8 * 128
    int logical = (b & 7) * 128 + (b >> 3);
    const int strip = logical >> 1, half = logical & 1;
    const int ct0 = half * 8 + w * 2;

    const ushort_t* xf0 = Xf + (size_t)(strip * 2) * KTILES * 512 + lane * 8;
    const ushort_t* xf1 = xf0 + (size_t)KTILES * 512;
    const ushort_t* wbp = Wb + (size_t)ct0 * 512 + lane * 8;

    f32x4 acc00 = (f32x4){0.f,0.f,0.f,0.f}, acc01 = acc00;
    f32x4 acc10 = acc00, acc11 = acc00;

    uint4 A0a, A1a, B0a, B1a, A0b, A1b, B0b, B1b;

    auto ld = [&](int kt, uint4& A0, uint4& A1, uint4& B0, uint4& B1) {
        A0 = *(const uint4*)(xf0 + (size_t)kt * 512);
        A1 = *(const uint4*)(xf1 + (size_t)kt * 512);
        B0 = *(const uint4*)(wbp + (size_t)kt * NCT * 512);
        B1 = *(const uint4*)(wbp + (size_t)kt * NCT * 512 + 512);
    };
    auto cp = [&](const uint4& A0, const uint4& A1, const uint4& B0, const uint4& B1) {
        bf16x8 a0 = *(const bf16x8*)&A0, a1 = *(const bf16x8*)&A1;
        bf16x8 f0 = *(const bf16x8*)&B0, f1 = *(const bf16x8*)&B1;
        acc00 = __builtin_amdgcn_mfma_f32_16x16x32_bf16(a0, f0, acc00, 0, 0, 0);
        acc01 = __builtin_amdgcn_mfma_f32_16x16x32_bf16(a0, f1, acc01, 0, 0, 0);
        acc10 = __builtin_amdgcn_mfma_f32_16x16x32_bf16(a1, f0, acc10, 0, 0, 0);
        acc11 = __builtin_amdgcn_mfma_f32_16x16x32_bf16(a1, f1, acc11, 0, 0, 0);
    };

    ld(0, A0a, A1a, B0a, B1a);
    for (int i = 0; i < 12; ++i) {
        ld(2 * i + 1, A0b, A1b, B0b, B1b);
        cp(A0a, A1a, B0a, B1a);
        ld(2 * i + 2, A0a, A1a, B0a, B1a);
        cp(A0b, A1b, B0b, B1b);
    }
    cp(A0a, A1a, B0a, B1a);                // kt = 24

    // epilogue: per-wave, fast softplus, direct atomics (no LDS, no barrier)
    const int jcol = lane & 15;
#pragma unroll
    for (int ctl = 0; ctl < 2; ++ctl) {
        int j = (ct0 + ctl) * 16 + jcol;
        float bias = (j < 100) ? b0[j] : ((j < 200) ? b1[j - 100] : 0.f);
        f32x4 u0 = ctl ? acc01 : acc00;
        f32x4 u1 = ctl ? acc11 : acc10;
        float v = 0.f;
#pragma unroll
        for (int r = 0; r < 4; ++r)
            v += softplus_fast(u0[r] + bias) + softplus_fast(u1[r] + bias);
        v += __shfl_xor(v, 16);
        v += __shfl_xor(v, 32);
        if ((lane >> 4) == 0 && j < 200) atomicAdd(&ws[j], v);
    }
}

// ---- colmean v2 (fallback when ws too small for Xf) ----
#define RED2(ws_, l_, c_) red[(((ws_) * 64) + (l_)) * 33 + (c_)]
__global__ __launch_bounds__(256, 4) void colmean_v2(
    const float* __restrict__ x, const ushort_t* __restrict__ Wb,
    const float* __restrict__ b0, const float* __restrict__ b1,
    float* __restrict__ ws)
{
    __shared__ float red[2 * 64 * 33];
    const int tid = threadIdx.x;
    const int lane = tid & 63, w = tid >> 6;
    int b = blockIdx.x;
    int logical = (b & 7) * 256 + (b >> 3);
    const int strip = logical >> 2, q = logical & 3;
    const float* xr0 = x + (size_t)(strip * 32 + (lane & 15)) * DIN;
    const float* xr1 = xr0 + (size_t)16 * DIN;
    const int kc = lane >> 4;

    f32x4 acc[2][4];
#pragma unroll
    for (int rg = 0; rg < 2; ++rg)
#pragma unroll
        for (int jj = 0; jj < 4; ++jj) acc[rg][jj] = (f32x4){0.f, 0.f, 0.f, 0.f};

    float4 Aa[4], Ab[4];
    uint4  Ba[4], Bb[4];
    auto loadA = [&](int kt, float4 (&A)[4]) {
        int k0 = kt * 32 + kc * 8;
        if (k0 + 8 > DIN) k0 = 768;
        A[0] = *(const float4*)(xr0 + k0);
        A[1] = *(const float4*)(xr0 + k0 + 4);
        A[2] = *(const float4*)(xr1 + k0);
        A[3] = *(const float4*)(xr1 + k0 + 4);
    };
    auto loadB = [&](int kt, uint4 (&B)[4]) {
#pragma unroll
        for (int jj = 0; jj < 4; ++jj)
            B[jj] = *(const uint4*)(Wb + ((size_t)((kt * NCT + q * 4 + jj) * 64 + lane)) * 8);
    };
    auto comp = [&](const float4 (&A)[4], const uint4 (&B)[4]) {
#pragma unroll
        for (int rg = 0; rg < 2; ++rg) {
            bf16x8 af; unsigned* p = (unsigned*)&af;
            p[0] = pack2(A[2 * rg].x, A[2 * rg].y);
            p[1] = pack2(A[2 * rg].z, A[2 * rg].w);
            p[2] = pack2(A[2 * rg + 1].x, A[2 * rg + 1].y);
            p[3] = pack2(A[2 * rg + 1].z, A[2 * rg + 1].w);
#pragma unroll
            for (int jj = 0; jj < 4; ++jj)
                acc[rg][jj] = __builtin_amdgcn_mfma_f32_16x16x32_bf16(
                    af, *(const bf16x8*)&B[jj], acc[rg][jj], 0, 0, 0);
        }
    };
    loadA(w, Aa); loadB(w, Ba);
#pragma unroll
    for (int i = 0; i < 3; ++i) {
        loadA(w + 4 * (2 * i + 1), Ab); loadB(w + 4 * (2 * i + 1), Bb);
        comp(Aa, Ba);
        loadA(w + 4 * (2 * i + 2), Aa); loadB(w + 4 * (2 * i + 2), Ba);
        comp(Ab, Bb);
    }
    comp(Aa, Ba);
    if (w >= 2) {
#pragma unroll
        for (int rg = 0; rg < 2; ++rg)
#pragma unroll
            for (int jj = 0; jj < 4; ++jj)
#pragma unroll
                for (int r = 0; r < 4; ++r)
                    RED2(w - 2, lane, rg * 16 + jj * 4 + r) = acc[rg][jj][r];
    }
    __syncthreads();
    if (w < 2) {
#pragma unroll
        for (int rg = 0; rg < 2; ++rg)
#pragma unroll
            for (int jj = 0; jj < 4; ++jj)
#pragma unroll
                for (int r = 0; r < 4; ++r)
                    acc[rg][jj][r] += RED2(w, lane, rg * 16 + jj * 4 + r);
    }
    __syncthreads();
    if (w == 1) {
#pragma unroll
        for (int rg = 0; rg < 2; ++rg)
#pragma unroll
            for (int jj = 0; jj < 4; ++jj)
#pragma unroll
                for (int r = 0; r < 4; ++r)
                    RED2(0, lane, rg * 16 + jj * 4 + r) = acc[rg][jj][r];
    }
    __syncthreads();
    if (w == 0) {
#pragma unroll
        for (int jj = 0; jj < 4; ++jj) {
            int j = (q * 4 + jj) * 16 + (lane & 15);
            float bias = (j < 100) ? b0[j] : ((j < 200) ? b1[j - 100] : 0.f);
            float v = 0.f;
#pragma unroll
            for (int rg = 0; rg < 2; ++rg)
#pragma unroll
                for (int r = 0; r < 4; ++r)
                    v += softplusf(acc[rg][jj][r] + RED2(0, lane, rg * 16 + jj * 4 + r) + bias);
            v += __shfl_xor(v, 16);
            v += __shfl_xor(v, 32);
            if ((lane >> 4) == 0 && j < 200) atomicAdd(&ws[j], v);
        }
    }
}

// ---- mean/cov, z, Dkl ----
__global__ __launch_bounds__(256) void middle_kernel(
    const float* __restrict__ eps, float* __restrict__ ws)
{
    __shared__ float red[256];
    const int tid = threadIdx.x;
    float contrib = 0.f;
    if (tid < DZ) {
        const float inv = 1.f / (float)NROWS;
        float mm = ws[tid] * inv;
        float cc = ws[100 + tid] * inv;
        contrib = 0.5f * __logf(cc);
#pragma unroll
        for (int s = 0; s < NS; ++s) {
            float e = eps[s * DZ + tid];
            float zz = mm + cc * e;
            ws[WS_Z + s * DZ + tid] = zz;
            contrib += (0.5f * cc * e * e - 0.5f * zz * zz) * (1.f / NS);
        }
    }
    red[tid] = contrib;
    __syncthreads();
    for (int off = 128; off > 0; off >>= 1) {
        if (tid < off) red[tid] += red[tid + off];
        __syncthreads();
    }
    if (tid == 0) ws[201] = red[0];
}

// ---- y2 = (z @ W2.T + b2) * log2e ----
__global__ __launch_bounds__(256) void y2_kernel(
    const float* __restrict__ W2, const float* __restrict__ b2,
    float* __restrict__ ws)
{
    int wid  = (int)((blockIdx.x * 256 + threadIdx.x) >> 6);
    int lane = threadIdx.x & 63;
    if (wid >= NS * DIN) return;
    int s = wid / DIN, i = wid % DIN;
    const float* zz = ws + WS_Z + s * DZ;
    const float* wr = W2 + (size_t)i * DZ;
    float p = 0.f;
    for (int d = lane; d < DZ; d += 64) p += zz[d] * wr[d];
#pragma unroll
    for (int off = 32; off > 0; off >>= 1) p += __shfl_xor(p, off);
    if (lane == 0) ws[WS_Y2 + wid] = (p + b2[i]) * 1.4426950408889634f;
}

// ---- pv v4: full-K-parity per wave from Xf, yf in LDS (|y| by masking) ----
// 512 blocks x 4 waves; wave = rowtile (w>>1) x K-parity (w&1). One barrier
// (yf stage) + one (pair reduce). Certified bound + exact fallback.
__global__ __launch_bounds__(256) void pv_v4(
    const float* __restrict__ x, const float* ws,
    const ushort_t* __restrict__ Xf, float* out_sum)
{
    __shared__ ushort_t yf[KTILES * 512];  // 25.6 KB
    __shared__ float red[4 * 64 * 9];      // 9.2 KB
    const int tid = threadIdx.x;
    const int lane = tid & 63, w = tid >> 6;

    for (int idx = tid; idx < KTILES * 64; idx += 256) {
        int kt = idx >> 6, l = idx & 63;
        int ss = l & 15, k0 = kt * 32 + (l >> 4) * 8;
        uint4 o = make_uint4(0u, 0u, 0u, 0u);
        if (ss < NS && k0 + 8 <= DIN) {
            const float* src = ws + WS_Y2 + (size_t)ss * DIN + k0;
            float4 a = *(const float4*)src, b2v = *(const float4*)(src + 4);
            o.x = pack2(a.x, a.y); o.y = pack2(a.z, a.w);
            o.z = pack2(b2v.x, b2v.y); o.w = pack2(b2v.z, b2v.w);
        }
        *(uint4*)(yf + (size_t)idx * 8) = o;
    }
    __syncthreads();

    int b = blockIdx.x;                    // XCD-bijective: 512 = 8 * 64
    const int tile32 = (b & 7) * 64 + (b >> 3);
    const int rt16 = tile32 * 2 + (w >> 1);
    const int kpar = w & 1;
    const ushort_t* xfr = Xf + (size_t)rt16 * KTILES * 512 + lane * 8;

    f32x4 acc0 = (f32x4){0.f, 0.f, 0.f, 0.f};
    f32x4 acc1 = (f32x4){0.f, 0.f, 0.f, 0.f};

    auto ustep = [&](int kt, const uint4& X) {
        bf16x8 nf; unsigned* p = (unsigned*)&nf;
        const unsigned* xw = (const unsigned*)&X;
#pragma unroll
        for (int i2 = 0; i2 < 4; ++i2) {
            float lo = __uint_as_float(xw[i2] << 16);
            float hi = __uint_as_float(xw[i2] & 0xFFFF0000u);
            p[i2] = pack2(1.f - 2.f * lo, 1.f - 2.f * hi);
        }
        bf16x8 na; unsigned* q = (unsigned*)&na;
        q[0] = p[0] & 0x7FFF7FFFu; q[1] = p[1] & 0x7FFF7FFFu;
        q[2] = p[2] & 0x7FFF7FFFu; q[3] = p[3] & 0x7FFF7FFFu;
        bf16x8 fy = *(const bf16x8*)(yf + (size_t)kt * 512 + lane * 8);
        bf16x8 fa; unsigned* fq = (unsigned*)&fa; const unsigned* fp = (const unsigned*)&fy;
        fq[0] = fp[0] & 0x7FFF7FFFu; fq[1] = fp[1] & 0x7FFF7FFFu;
        fq[2] = fp[2] & 0x7FFF7FFFu; fq[3] = fp[3] & 0x7FFF7FFFu;
        acc0 = __builtin_amdgcn_mfma_f32_16x16x32_bf16(nf, fy, acc0, 0, 0, 0);
        acc1 = __builtin_amdgcn_mfma_f32_16x16x32_bf16(na, fa, acc1, 0, 0, 0);
    };

    uint4 Xa, Xb;
    Xa = *(const uint4*)(xfr + (size_t)kpar * 512);
    int kt = kpar;
    for (; kt + 2 <= 24; kt += 2) {
        Xb = *(const uint4*)(xfr + (size_t)(kt + 2) * 512);
        ustep(kt, Xa);
        Xa = Xb;
    }
    ustep(kt, Xa);                         // last kt (24 or 23)

#pragma unroll
    for (int r = 0; r < 4; ++r) {
        red[(w * 64 + lane) * 9 + r]     = acc0[r];
        red[(w * 64 + lane) * 9 + 4 + r] = acc1[r];
    }
    __syncthreads();

    if (w < 2) {                           // finalize wave w handles rowtile tile32*2+w
        const int f = w;
        const int myrt = tile32 * 2 + f;
        const int s = lane & 15;
        const float L001 = -6.90775527898f;
        float bnd[4];
#pragma unroll
        for (int r = 0; r < 4; ++r) {
            float s0 = red[((2 * f) * 64 + lane) * 9 + r]
                     + red[((2 * f + 1) * 64 + lane) * 9 + r];
            float s1 = red[((2 * f) * 64 + lane) * 9 + 4 + r]
                     + red[((2 * f + 1) * 64 + lane) * 9 + 4 + r];
            bnd[r] = 0.5f * (s0 + s1);
        }
        float wsum;
        bool lslow = (s < NS) &&
            (fminf(fminf(bnd[0], bnd[1]), fminf(bnd[2], bnd[3])) < BND_THR);
        unsigned long long m = __ballot(lslow);
        m &= 0xFFFFFFFFFFFFFFFFull;        // all lanes of this wave
        if (m == 0ull) {
            wsum = 160.f * L001;           // 16 rows x 10 samples certified
        } else {
            int nslow = 0;
            float slowsum = 0.f;
#pragma unroll
            for (int r = 0; r < 4; ++r) {
                unsigned long long mr = __ballot((s < NS) && (bnd[r] < BND_THR));
                nslow += (int)__popcll(mr);
                while (mr) {
                    int src = (int)__ffsll(mr) - 1; mr &= (mr - 1);
                    int ss = src & 15;
                    int rrow = myrt * 16 + (src >> 4) * 4 + r;
                    const float* xq = x + (size_t)rrow * DIN;
                    const float* yq = ws + WS_Y2 + (size_t)ss * DIN;
                    float a = 0.f;
                    for (int i = lane; i < DIN; i += 64)
                        a -= __builtin_amdgcn_logf(
                            1.f + __builtin_amdgcn_exp2f((1.f - 2.f * xq[i]) * yq[i]));
#pragma unroll
                    for (int off = 32; off > 0; off >>= 1) a += __shfl_xor(a, off);
                    slowsum += __logf(__builtin_amdgcn_exp2f(a) + 0.001f);
                }
            }
            wsum = (float)(160 - nslow) * L001 + slowsum;
        }
        if (lane == 0) atomicAdd(out_sum, wsum);
    }
}

// ---- pv fallback (R5 version) ----
__global__ __launch_bounds__(256, 4) void pv_old(
    const float* __restrict__ x, const float* ws, float* out_sum)
{
    __shared__ ushort_t yf[KTILES * 512];
    __shared__ ushort_t ya[KTILES * 512];
    __shared__ float bsum;
    const int tid = threadIdx.x;
    const int lane = tid & 63, w = tid >> 6;

    for (int idx = tid; idx < KTILES * 64; idx += 256) {
        int kt = idx >> 6, l = idx & 63;
        int ss = l & 15, k0 = kt * 32 + (l >> 4) * 8;
        uint4 o = make_uint4(0u, 0u, 0u, 0u), oa = o;
        if (ss < NS && k0 < DIN) {
            const float* src = ws + WS_Y2 + ss * DIN + k0;
            float4 a = *(const float4*)src, b = *(const float4*)(src + 4);
            o.x = pack2(a.x, a.y); o.y = pack2(a.z, a.w);
            o.z = pack2(b.x, b.y); o.w = pack2(b.z, b.w);
            oa.x = o.x & 0x7FFF7FFFu; oa.y = o.y & 0x7FFF7FFFu;
            oa.z = o.z & 0x7FFF7FFFu; oa.w = o.w & 0x7FFF7FFFu;
        }
        *(uint4*)(yf + (size_t)idx * 8) = o;
        *(uint4*)(ya + (size_t)idx * 8) = oa;
    }
    if (tid == 0) bsum = 0.f;
    __syncthreads();

    const int tile = blockIdx.x * 4 + w;
    const int row  = tile * 16 + (lane & 15);
    const int kc   = lane >> 4;
    const int s    = lane & 15;
    const float* xp = x + (size_t)row * DIN;
    const float L001 = -6.90775527898f;

    f32x4 acc0 = (f32x4){0.f, 0.f, 0.f, 0.f};
    f32x4 acc1 = (f32x4){0.f, 0.f, 0.f, 0.f};
    float4 a0A, a1A, a0B, a1B;

    auto loadA = [&](int kt, float4& a0, float4& a1) {
        int k0 = kt * 32 + kc * 8;
        if (k0 + 8 > DIN) k0 = 768;
        a0 = *(const float4*)(xp + k0);
        a1 = *(const float4*)(xp + k0 + 4);
    };
    auto comp = [&](int kt, const float4& a0, const float4& a1) {
        bf16x8 nf; unsigned* p = (unsigned*)&nf;
        p[0] = pack2(1.f - 2.f * a0.x, 1.f - 2.f * a0.y);
        p[1] = pack2(1.f - 2.f * a0.z, 1.f - 2.f * a0.w);
        p[2] = pack2(1.f - 2.f * a1.x, 1.f - 2.f * a1.y);
        p[3] = pack2(1.f - 2.f * a1.z, 1.f - 2.f * a1.w);
        bf16x8 na; unsigned* q = (unsigned*)&na;
        q[0] = p[0] & 0x7FFF7FFFu; q[1] = p[1] & 0x7FFF7FFFu;
        q[2] = p[2] & 0x7FFF7FFFu; q[3] = p[3] & 0x7FFF7FFFu;
        bf16x8 fy = *(const bf16x8*)(yf + (size_t)kt * 512 + lane * 8);
        bf16x8 fa = *(const bf16x8*)(ya + (size_t)kt * 512 + lane * 8);
        acc0 = __builtin_amdgcn_mfma_f32_16x16x32_bf16(nf, fy, acc0, 0, 0, 0);
        acc1 = __builtin_amdgcn_mfma_f32_16x16x32_bf16(na, fa, acc1, 0, 0, 0);
    };
    loadA(0, a0A, a1A);
    for (int i = 0; i < 12; ++i) {
        loadA(2 * i + 1, a0B, a1B);
        comp(2 * i, a0A, a1A);
        loadA(2 * i + 2, a0A, a1A);
        comp(2 * i + 1, a0B, a1B);
    }
    comp(24, a0A, a1A);

    float bnd[4];
#pragma unroll
    for (int r = 0; r < 4; ++r) bnd[r] = 0.5f * (acc0[r] + acc1[r]);
    float wsum;
    bool lslow = (s < NS) &&
        (fminf(fminf(bnd[0], bnd[1]), fminf(bnd[2], bnd[3])) < BND_THR);
    unsigned long long m = __ballot(lslow);
    if (m == 0ull) {
        wsum = 160.f * L001;
    } else {
        int nslow = 0;
        float slowsum = 0.f;
#pragma unroll
        for (int r = 0; r < 4; ++r) {
            unsigned long long mr = __ballot((s < NS) && (bnd[r] < BND_THR));
            nslow += (int)__popcll(mr);
            while (mr) {
                int src = (int)__ffsll(mr) - 1; mr &= (mr - 1);
                int ss = src & 15;
                int rrow = tile * 16 + (src >> 4) * 4 + r;
                const float* xq = x + (size_t)rrow * DIN;
                const float* yq = ws + WS_Y2 + ss * DIN;
                float a = 0.f;
                for (int i = lane; i < DIN; i += 64)
                    a -= __builtin_amdgcn_logf(
                        1.f + __builtin_amdgcn_exp2f((1.f - 2.f * xq[i]) * yq[i]));
#pragma unroll
                for (int off = 32; off > 0; off >>= 1) a += __shfl_xor(a, off);
                slowsum += __logf(__builtin_amdgcn_exp2f(a) + 0.001f);
            }
        }
        wsum = (float)(160 - nslow) * L001 + slowsum;
    }
    if (lane == 0) atomicAdd(&bsum, wsum);
    __syncthreads();
    if (tid == 0) atomicAdd(out_sum, bsum);
}

// ---- final scalar ----
__global__ void final_kernel(const float* __restrict__ ws, float* __restrict__ out)
{
    float E = ws[200] * (1.f / ((float)NROWS * (float)NS));
    out[0] = -(E + ws[201]);
}

extern "C" void kernel_launch(void* const* d_in, const int* in_sizes, int n_in,
                              void* d_out, int out_size, void* d_ws, size_t ws_size,
                              hipStream_t stream)
{
    const float* x   = (const float*)d_in[0];
    const float* W0  = (const float*)d_in[1];
    const float* b0  = (const float*)d_in[2];
    const float* W1  = (const float*)d_in[3];
    const float* b1  = (const float*)d_in[4];
    const float* W2  = (const float*)d_in[5];
    const float* b2  = (const float*)d_in[6];
    const float* eps = (const float*)d_in[7];
    float* out = (float*)d_out;
    float* ws  = (float*)d_ws;
    ushort_t* Wb = (ushort_t*)((char*)d_ws + WB_OFF_BYTES);
    ushort_t* Xf = (ushort_t*)((char*)d_ws + XF_OFF_BYTES);

    hipMemsetAsync(ws, 0, 512 * sizeof(float), stream);

    if (ws_size >= WS_NEED_BYTES) {
        prep_kernel<<<WB_BLOCKS + XF_BLOCKS, 256, 0, stream>>>(W0, W1, x, Wb, Xf, 1);
        colmean_v4<<<1024, 256, 0, stream>>>(Xf, Wb, b0, b1, ws);
        middle_kernel<<<1, 256, 0, stream>>>(eps, ws);
        y2_kernel<<<(NS * DIN * 64) / 256, 256, 0, stream>>>(W2, b2, ws);
        pv_v4<<<512, 256, 0, stream>>>(x, ws, Xf, ws + 200);
    } else {
        prep_kernel<<<WB_BLOCKS, 256, 0, stream>>>(W0, W1, x, Wb, Xf, 0);
        colmean_v2<<<2048, 256, 0, stream>>>(x, Wb, b0, b1, ws);
        middle_kernel<<<1, 256, 0, stream>>>(eps, ws);
        y2_kernel<<<(NS * DIN * 64) / 256, 256, 0, stream>>>(W2, b2, ws);
        pv_old<<<256, 256, 0, stream>>>(x, ws, ws + 200);
    }
    final_kernel<<<1, 1, 0, stream>>>(ws, out);
}

// Round 12
// 61.414 us; speedup vs baseline: 1.7495x; 1.3598x over previous
//
#include <hip/hip_runtime.h>
#include <hip/hip_bf16.h>
#include <math.h>

#define NROWS 16384
#define DIN   784
#define DZ    100
#define NS    10
#define NCT   16           // 16 col-tiles x 16 = 256 cols (200 real + 56 zero pad)
#define KTILES 25          // 25 * 32 = 800 >= 784, tail frags zeroed
#define BND_THR 45.0f

typedef unsigned short ushort_t;
typedef short bf16x8 __attribute__((ext_vector_type(8)));
typedef float f32x4  __attribute__((ext_vector_type(4)));

// ws layout:
//  floats [0..199] colsum softplus (atomic)  [200] pv log-sum  [201] Dkl
//  floats [208..8047] y2[s][i] = y*log2e     [8064..9063] z[s][d]
//  byte 64KB..: Wb bf16 frag-swizzled W, 25*16*512 ushorts (400 KB)
#define WS_Y2 208
#define WS_Z  8064
#define WB_OFF_BYTES (64u * 1024u)

__device__ __forceinline__ float softplus_fast(float v) {
    // ln(1+e^v) = (max(t,0) + log2(1+2^-|t|)) * ln2, t = v*log2e  (v_exp/v_log pipes)
    float t = v * 1.44269504088896f;
    return (fmaxf(t, 0.f)
            + __builtin_amdgcn_logf(1.f + __builtin_amdgcn_exp2f(-fabsf(t))))
           * 0.69314718055995f;
}
__device__ __forceinline__ unsigned pack2(float lo, float hi) {
    float2 f2; f2.x = lo; f2.y = hi;
    __hip_bfloat162 h2 = __float22bfloat162_rn(f2);
    return *reinterpret_cast<unsigned*>(&h2);
}

// ---- W -> bf16, MFMA B-fragment order ----
// Wb[((kt*16 + ct)*64 + l)*8 + j] = W[ct*16 + (l&15)][kt*32 + (l>>4)*8 + j]
__global__ __launch_bounds__(256) void wb_kernel(
    const float* __restrict__ W0, const float* __restrict__ W1, ushort_t* __restrict__ Wb)
{
    int t = blockIdx.x * 256 + threadIdx.x;
    if (t >= KTILES * NCT * 64) return;
    int kt = t >> 10;
    int r  = t & 1023;
    int ct = r >> 6, l = r & 63;
    int col = ct * 16 + (l & 15);
    int k0  = kt * 32 + (l >> 4) * 8;
    uint4 o = make_uint4(0u, 0u, 0u, 0u);
    if (col < 200 && k0 < DIN) {
        const float* src = (col < 100 ? W0 + (size_t)col * DIN
                                      : W1 + (size_t)(col - 100) * DIN) + k0;
        float4 a = *(const float4*)src;
        float4 b = *(const float4*)(src + 4);
        o.x = pack2(a.x, a.y); o.y = pack2(a.z, a.w);
        o.z = pack2(b.x, b.y); o.w = pack2(b.z, b.w);
    }
    *(uint4*)(Wb + (size_t)t * 8) = o;
}

// ---- colmean fused: stage-once LDS transpose + barrier-free K-loop ----
// 512 blocks x 512 thr (8 waves). Block = 32 rows x all 16 col-tiles.
// Stage: coalesced x float4 reads -> bf16 A-frags in LDS (51.2 KB), ONE barrier.
// K-loop: wave w = col-tiles {2w,2w+1} x both rowtiles; per kt: 2 ds_read_b128 +
// 2 coalesced B loads (L2-resident Wb) + 4 MFMA; named reg dbuf, zero barriers.
__global__ __launch_bounds__(512) void colmean_f(
    const float* __restrict__ x, const ushort_t* __restrict__ Wb,
    const float* __restrict__ b0, const float* __restrict__ b1,
    float* __restrict__ ws)
{
    __shared__ ushort_t xls[2 * KTILES * 512];   // [rt][kt][lane][8] bf16
    const int tid = threadIdx.x;
    const int lane = tid & 63, w = tid >> 6;
    const int row0 = blockIdx.x * 32;

    // ---- stage ----
    for (int slot = tid; slot < 3200; slot += 512) {   // slot = r*100 + kt*4 + kc
        int r  = slot / 100;
        int sl = slot - r * 100;
        int kt = sl >> 2, kc = sl & 3;
        int k0 = kt * 32 + kc * 8;
        uint4 o = make_uint4(0u, 0u, 0u, 0u);
        if (k0 + 8 <= DIN) {
            const float* src = x + (size_t)(row0 + r) * DIN + k0;
            float4 a = *(const float4*)src, b = *(const float4*)(src + 4);
            o.x = pack2(a.x, a.y); o.y = pack2(a.z, a.w);
            o.z = pack2(b.x, b.y); o.w = pack2(b.z, b.w);
        }
        int l = (kc << 4) | (r & 15);
        *(uint4*)&xls[((size_t)(r >> 4) * KTILES + kt) * 512 + l * 8] = o;
    }
    __syncthreads();

    // ---- K-loop ----
    const int ct0 = w * 2;
    const ushort_t* a0p = xls + lane * 8;                    // rt0, + kt*512
    const ushort_t* a1p = xls + KTILES * 512 + lane * 8;     // rt1
    const ushort_t* wbp = Wb + (size_t)ct0 * 512 + lane * 8; // + kt*8192, +512/ct

    f32x4 acc00 = (f32x4){0.f,0.f,0.f,0.f}, acc01 = acc00;
    f32x4 acc10 = acc00, acc11 = acc00;

    bf16x8 A0a, A1a, A0b, A1b;
    uint4  B0a, B1a, B0b, B1b;

    auto ld = [&](int kt, bf16x8& A0, bf16x8& A1, uint4& B0, uint4& B1) {
        A0 = *(const bf16x8*)(a0p + (size_t)kt * 512);
        A1 = *(const bf16x8*)(a1p + (size_t)kt * 512);
        B0 = *(const uint4*)(wbp + (size_t)kt * 8192);
        B1 = *(const uint4*)(wbp + (size_t)kt * 8192 + 512);
    };
    auto cp = [&](const bf16x8& A0, const bf16x8& A1, const uint4& B0, const uint4& B1) {
        bf16x8 f0 = *(const bf16x8*)&B0, f1 = *(const bf16x8*)&B1;
        acc00 = __builtin_amdgcn_mfma_f32_16x16x32_bf16(A0, f0, acc00, 0, 0, 0);
        acc01 = __builtin_amdgcn_mfma_f32_16x16x32_bf16(A0, f1, acc01, 0, 0, 0);
        acc10 = __builtin_amdgcn_mfma_f32_16x16x32_bf16(A1, f0, acc10, 0, 0, 0);
        acc11 = __builtin_amdgcn_mfma_f32_16x16x32_bf16(A1, f1, acc11, 0, 0, 0);
    };

    ld(0, A0a, A1a, B0a, B1a);
    for (int i = 0; i < 12; ++i) {
        ld(2 * i + 1, A0b, A1b, B0b, B1b);
        cp(A0a, A1a, B0a, B1a);
        ld(2 * i + 2, A0a, A1a, B0a, B1a);
        cp(A0b, A1b, B0b, B1b);
    }
    cp(A0a, A1a, B0a, B1a);                // kt = 24

    // ---- epilogue: fast softplus, 16+16 row reduce via shfl, atomics ----
    const int jcol = lane & 15;
#pragma unroll
    for (int ctl = 0; ctl < 2; ++ctl) {
        int j = (ct0 + ctl) * 16 + jcol;
        float bias = (j < 100) ? b0[j] : ((j < 200) ? b1[j - 100] : 0.f);
        f32x4 u0 = ctl ? acc01 : acc00;
        f32x4 u1 = ctl ? acc11 : acc10;
        float v = 0.f;
#pragma unroll
        for (int r = 0; r < 4; ++r)
            v += softplus_fast(u0[r] + bias) + softplus_fast(u1[r] + bias);
        v += __shfl_xor(v, 16);
        v += __shfl_xor(v, 32);
        if ((lane >> 4) == 0 && j < 200) atomicAdd(&ws[j], v);
    }
}

// ---- mean/cov, z, Dkl ----
__global__ __launch_bounds__(256) void middle_kernel(
    const float* __restrict__ eps, float* __restrict__ ws)
{
    __shared__ float red[256];
    const int tid = threadIdx.x;
    float contrib = 0.f;
    if (tid < DZ) {
        const float inv = 1.f / (float)NROWS;
        float mm = ws[tid] * inv;
        float cc = ws[100 + tid] * inv;
        contrib = 0.5f * __logf(cc);
#pragma unroll
        for (int s = 0; s < NS; ++s) {
            float e = eps[s * DZ + tid];
            float zz = mm + cc * e;
            ws[WS_Z + s * DZ + tid] = zz;
            contrib += (0.5f * cc * e * e - 0.5f * zz * zz) * (1.f / NS);
        }
    }
    red[tid] = contrib;
    __syncthreads();
    for (int off = 128; off > 0; off >>= 1) {
        if (tid < off) red[tid] += red[tid + off];
        __syncthreads();
    }
    if (tid == 0) ws[201] = red[0];
}

// ---- y2 = (z @ W2.T + b2) * log2e ----
__global__ __launch_bounds__(256) void y2_kernel(
    const float* __restrict__ W2, const float* __restrict__ b2,
    float* __restrict__ ws)
{
    int wid  = (int)((blockIdx.x * 256 + threadIdx.x) >> 6);
    int lane = threadIdx.x & 63;
    if (wid >= NS * DIN) return;
    int s = wid / DIN, i = wid % DIN;
    const float* zz = ws + WS_Z + s * DZ;
    const float* wr = W2 + (size_t)i * DZ;
    float p = 0.f;
    for (int d = lane; d < DZ; d += 64) p += zz[d] * wr[d];
#pragma unroll
    for (int off = 32; off > 0; off >>= 1) p += __shfl_xor(p, off);
    if (lane == 0) ws[WS_Y2 + wid] = (p + b2[i]) * 1.4426950408889634f;
}

// ---- pv (proven R5 shape): MFMA-certified bound + rare exact fallback ----
// sum_i max(u,0) = 0.5*(n.y + |n|.|y|), u=(1-2x)*y2 (log2 units). bnd >= 45 =>
// p < 2^-43 << ulp(0.001)/2 => term == ln(0.001) exactly (ref prod underflows).
__global__ __launch_bounds__(256, 4) void pv_kernel(
    const float* __restrict__ x, const float* ws, float* out_sum)
{
    __shared__ ushort_t yf[KTILES * 512];   // y2 B-frags (bf16)
    __shared__ ushort_t ya[KTILES * 512];   // |y2| B-frags
    __shared__ float bsum;
    const int tid = threadIdx.x;
    const int lane = tid & 63, w = tid >> 6;

    for (int idx = tid; idx < KTILES * 64; idx += 256) {
        int kt = idx >> 6, l = idx & 63;
        int ss = l & 15, k0 = kt * 32 + (l >> 4) * 8;
        uint4 o = make_uint4(0u, 0u, 0u, 0u), oa = o;
        if (ss < NS && k0 < DIN) {
            const float* src = ws + WS_Y2 + ss * DIN + k0;
            float4 a = *(const float4*)src, b = *(const float4*)(src + 4);
            o.x = pack2(a.x, a.y); o.y = pack2(a.z, a.w);
            o.z = pack2(b.x, b.y); o.w = pack2(b.z, b.w);
            oa.x = o.x & 0x7FFF7FFFu; oa.y = o.y & 0x7FFF7FFFu;
            oa.z = o.z & 0x7FFF7FFFu; oa.w = o.w & 0x7FFF7FFFu;
        }
        *(uint4*)(yf + (size_t)idx * 8) = o;
        *(uint4*)(ya + (size_t)idx * 8) = oa;
    }
    if (tid == 0) bsum = 0.f;
    __syncthreads();

    const int tile = blockIdx.x * 4 + w;       // 1024 tiles of 16 rows
    const int row  = tile * 16 + (lane & 15);
    const int kc   = lane >> 4;
    const int s    = lane & 15;
    const float* xp = x + (size_t)row * DIN;
    const float L001 = -6.90775527898f;        // ln(0.001f)

    f32x4 acc0 = (f32x4){0.f, 0.f, 0.f, 0.f};
    f32x4 acc1 = (f32x4){0.f, 0.f, 0.f, 0.f};
    float4 a0A, a1A, a0B, a1B;

    auto loadA = [&](int kt, float4& a0, float4& a1) {
        int k0 = kt * 32 + kc * 8;
        if (k0 + 8 > DIN) k0 = 768;            // junk ok: y frags zero there
        a0 = *(const float4*)(xp + k0);
        a1 = *(const float4*)(xp + k0 + 4);
    };
    auto comp = [&](int kt, const float4& a0, const float4& a1) {
        bf16x8 nf; unsigned* p = (unsigned*)&nf;
        p[0] = pack2(1.f - 2.f * a0.x, 1.f - 2.f * a0.y);
        p[1] = pack2(1.f - 2.f * a0.z, 1.f - 2.f * a0.w);
        p[2] = pack2(1.f - 2.f * a1.x, 1.f - 2.f * a1.y);
        p[3] = pack2(1.f - 2.f * a1.z, 1.f - 2.f * a1.w);
        bf16x8 na; unsigned* q = (unsigned*)&na;
        q[0] = p[0] & 0x7FFF7FFFu; q[1] = p[1] & 0x7FFF7FFFu;
        q[2] = p[2] & 0x7FFF7FFFu; q[3] = p[3] & 0x7FFF7FFFu;
        bf16x8 fy = *(const bf16x8*)(yf + (size_t)kt * 512 + lane * 8);
        bf16x8 fa = *(const bf16x8*)(ya + (size_t)kt * 512 + lane * 8);
        acc0 = __builtin_amdgcn_mfma_f32_16x16x32_bf16(nf, fy, acc0, 0, 0, 0);
        acc1 = __builtin_amdgcn_mfma_f32_16x16x32_bf16(na, fa, acc1, 0, 0, 0);
    };

    loadA(0, a0A, a1A);
    for (int i = 0; i < 12; ++i) {
        loadA(2 * i + 1, a0B, a1B);
        comp(2 * i, a0A, a1A);
        loadA(2 * i + 2, a0A, a1A);
        comp(2 * i + 1, a0B, a1B);
    }
    comp(24, a0A, a1A);

    float bnd[4];
#pragma unroll
    for (int r = 0; r < 4; ++r) bnd[r] = 0.5f * (acc0[r] + acc1[r]);

    float wsum;
    bool lslow = (s < NS) &&
        (fminf(fminf(bnd[0], bnd[1]), fminf(bnd[2], bnd[3])) < BND_THR);
    unsigned long long m = __ballot(lslow);
    if (m == 0ull) {
        wsum = 160.f * L001;                   // 16 rows x 10 samples, all certified
    } else {
        int nslow = 0;
        float slowsum = 0.f;
#pragma unroll
        for (int r = 0; r < 4; ++r) {
            unsigned long long mr = __ballot((s < NS) && (bnd[r] < BND_THR));
            nslow += (int)__popcll(mr);
            while (mr) {
                int src = (int)__ffsll(mr) - 1; mr &= (mr - 1);
                int ss = src & 15;
                int rrow = tile * 16 + (src >> 4) * 4 + r;
                const float* xq = x + (size_t)rrow * DIN;
                const float* yq = ws + WS_Y2 + ss * DIN;
                float a = 0.f;
                for (int i = lane; i < DIN; i += 64)
                    a -= __builtin_amdgcn_logf(
                        1.f + __builtin_amdgcn_exp2f((1.f - 2.f * xq[i]) * yq[i]));
#pragma unroll
                for (int off = 32; off > 0; off >>= 1) a += __shfl_xor(a, off);
                slowsum += __logf(__builtin_amdgcn_exp2f(a) + 0.001f);
            }
        }
        wsum = (float)(160 - nslow) * L001 + slowsum;
    }
    if (lane == 0) atomicAdd(&bsum, wsum);
    __syncthreads();
    if (tid == 0) atomicAdd(out_sum, bsum);
}

// ---- final scalar ----
__global__ void final_kernel(const float* __restrict__ ws, float* __restrict__ out)
{
    float E = ws[200] * (1.f / ((float)NROWS * (float)NS));
    out[0] = -(E + ws[201]);
}

extern "C" void kernel_launch(void* const* d_in, const int* in_sizes, int n_in,
                              void* d_out, int out_size, void* d_ws, size_t ws_size,
                              hipStream_t stream)
{
    const float* x   = (const float*)d_in[0];
    const float* W0  = (const float*)d_in[1];
    const float* b0  = (const float*)d_in[2];
    const float* W1  = (const float*)d_in[3];
    const float* b1  = (const float*)d_in[4];
    const float* W2  = (const float*)d_in[5];
    const float* b2  = (const float*)d_in[6];
    const float* eps = (const float*)d_in[7];
    float* out = (float*)d_out;
    float* ws  = (float*)d_ws;
    ushort_t* Wb = (ushort_t*)((char*)d_ws + WB_OFF_BYTES);

    hipMemsetAsync(ws, 0, 512 * sizeof(float), stream);
    wb_kernel<<<(KTILES * NCT * 64 + 255) / 256, 256, 0, stream>>>(W0, W1, Wb);
    colmean_f<<<NROWS / 32, 512, 0, stream>>>(x, Wb, b0, b1, ws);
    middle_kernel<<<1, 256, 0, stream>>>(eps, ws);
    y2_kernel<<<(NS * DIN * 64) / 256, 256, 0, stream>>>(W2, b2, ws);
    pv_kernel<<<256, 256, 0, stream>>>(x, ws, ws + 200);
    final_kernel<<<1, 1, 0, stream>>>(ws, out);
}

// Round 13
// 60.128 us; speedup vs baseline: 1.7870x; 1.0214x over previous
//
#include <hip/hip_runtime.h>
#include <hip/hip_bf16.h>
#include <math.h>

#define NROWS 16384
#define DIN   784
#define DZ    100
#define NS    10
#define NCT   16           // 16 col-tiles x 16 = 256 cols (200 real + 56 zero pad)
#define KTILES 25          // 25 * 32 = 800 >= 784, tail frags zeroed
#define BND_THR 45.0f

typedef unsigned short ushort_t;
typedef short bf16x8 __attribute__((ext_vector_type(8)));
typedef float f32x4  __attribute__((ext_vector_type(4)));

// ws layout:
//  floats [0..199] colsum softplus (atomic)  [200] pv log-sum  [202] done-counter
//  floats [208..8047] y2[s][i] = y*log2e
//  byte 64KB..: Wb bf16 frag-swizzled W, 25*16*512 ushorts (400 KB)
#define WS_Y2 208
#define WB_OFF_BYTES (64u * 1024u)

__device__ __forceinline__ float softplus_fast(float v) {
    // ln(1+e^v) = (max(t,0) + log2(1+2^-|t|)) * ln2, t = v*log2e  (v_exp/v_log pipes)
    float t = v * 1.44269504088896f;
    return (fmaxf(t, 0.f)
            + __builtin_amdgcn_logf(1.f + __builtin_amdgcn_exp2f(-fabsf(t))))
           * 0.69314718055995f;
}
__device__ __forceinline__ unsigned pack2(float lo, float hi) {
    float2 f2; f2.x = lo; f2.y = hi;
    __hip_bfloat162 h2 = __float22bfloat162_rn(f2);
    return *reinterpret_cast<unsigned*>(&h2);
}

// ---- W -> bf16 B-frags + ws zero (absorbs the memset dispatch) ----
// Wb[((kt*16 + ct)*64 + l)*8 + j] = W[ct*16 + (l&15)][kt*32 + (l>>4)*8 + j]
__global__ __launch_bounds__(256) void wb_kernel(
    const float* __restrict__ W0, const float* __restrict__ W1,
    ushort_t* __restrict__ Wb, float* __restrict__ ws)
{
    if (blockIdx.x == 0) ws[threadIdx.x] = 0.f;    // [0..255]: sums + counter
    int t = blockIdx.x * 256 + threadIdx.x;
    if (t >= KTILES * NCT * 64) return;
    int kt = t >> 10;
    int r  = t & 1023;
    int ct = r >> 6, l = r & 63;
    int col = ct * 16 + (l & 15);
    int k0  = kt * 32 + (l >> 4) * 8;
    uint4 o = make_uint4(0u, 0u, 0u, 0u);
    if (col < 200 && k0 < DIN) {
        const float* src = (col < 100 ? W0 + (size_t)col * DIN
                                      : W1 + (size_t)(col - 100) * DIN) + k0;
        float4 a = *(const float4*)src;
        float4 b = *(const float4*)(src + 4);
        o.x = pack2(a.x, a.y); o.y = pack2(a.z, a.w);
        o.z = pack2(b.x, b.y); o.w = pack2(b.z, b.w);
    }
    *(uint4*)(Wb + (size_t)t * 8) = o;
}

// ---- colmean fused: stage-once LDS transpose + barrier-free K-loop (R12-proven) ----
__global__ __launch_bounds__(512) void colmean_f(
    const float* __restrict__ x, const ushort_t* __restrict__ Wb,
    const float* __restrict__ b0, const float* __restrict__ b1,
    float* __restrict__ ws)
{
    __shared__ ushort_t xls[2 * KTILES * 512];   // [rt][kt][lane][8] bf16
    const int tid = threadIdx.x;
    const int lane = tid & 63, w = tid >> 6;
    const int row0 = blockIdx.x * 32;

    // ---- stage: coalesced x reads -> frag-linear LDS, ONE barrier ----
    for (int slot = tid; slot < 3200; slot += 512) {   // slot = r*100 + kt*4 + kc
        int r  = slot / 100;
        int sl = slot - r * 100;
        int kt = sl >> 2, kc = sl & 3;
        int k0 = kt * 32 + kc * 8;
        uint4 o = make_uint4(0u, 0u, 0u, 0u);
        if (k0 + 8 <= DIN) {
            const float* src = x + (size_t)(row0 + r) * DIN + k0;
            float4 a = *(const float4*)src, b = *(const float4*)(src + 4);
            o.x = pack2(a.x, a.y); o.y = pack2(a.z, a.w);
            o.z = pack2(b.x, b.y); o.w = pack2(b.z, b.w);
        }
        int l = (kc << 4) | (r & 15);
        *(uint4*)&xls[((size_t)(r >> 4) * KTILES + kt) * 512 + l * 8] = o;
    }
    __syncthreads();

    // ---- K-loop: zero barriers, named reg dbuf ----
    const int ct0 = w * 2;
    const ushort_t* a0p = xls + lane * 8;
    const ushort_t* a1p = xls + KTILES * 512 + lane * 8;
    const ushort_t* wbp = Wb + (size_t)ct0 * 512 + lane * 8;

    f32x4 acc00 = (f32x4){0.f,0.f,0.f,0.f}, acc01 = acc00;
    f32x4 acc10 = acc00, acc11 = acc00;

    bf16x8 A0a, A1a, A0b, A1b;
    uint4  B0a, B1a, B0b, B1b;

    auto ld = [&](int kt, bf16x8& A0, bf16x8& A1, uint4& B0, uint4& B1) {
        A0 = *(const bf16x8*)(a0p + (size_t)kt * 512);
        A1 = *(const bf16x8*)(a1p + (size_t)kt * 512);
        B0 = *(const uint4*)(wbp + (size_t)kt * 8192);
        B1 = *(const uint4*)(wbp + (size_t)kt * 8192 + 512);
    };
    auto cp = [&](const bf16x8& A0, const bf16x8& A1, const uint4& B0, const uint4& B1) {
        bf16x8 f0 = *(const bf16x8*)&B0, f1 = *(const bf16x8*)&B1;
        acc00 = __builtin_amdgcn_mfma_f32_16x16x32_bf16(A0, f0, acc00, 0, 0, 0);
        acc01 = __builtin_amdgcn_mfma_f32_16x16x32_bf16(A0, f1, acc01, 0, 0, 0);
        acc10 = __builtin_amdgcn_mfma_f32_16x16x32_bf16(A1, f0, acc10, 0, 0, 0);
        acc11 = __builtin_amdgcn_mfma_f32_16x16x32_bf16(A1, f1, acc11, 0, 0, 0);
    };

    ld(0, A0a, A1a, B0a, B1a);
    for (int i = 0; i < 12; ++i) {
        ld(2 * i + 1, A0b, A1b, B0b, B1b);
        cp(A0a, A1a, B0a, B1a);
        ld(2 * i + 2, A0a, A1a, B0a, B1a);
        cp(A0b, A1b, B0b, B1b);
    }
    cp(A0a, A1a, B0a, B1a);                // kt = 24

    // ---- epilogue ----
    const int jcol = lane & 15;
#pragma unroll
    for (int ctl = 0; ctl < 2; ++ctl) {
        int j = (ct0 + ctl) * 16 + jcol;
        float bias = (j < 100) ? b0[j] : ((j < 200) ? b1[j - 100] : 0.f);
        f32x4 u0 = ctl ? acc01 : acc00;
        f32x4 u1 = ctl ? acc11 : acc10;
        float v = 0.f;
#pragma unroll
        for (int r = 0; r < 4; ++r)
            v += softplus_fast(u0[r] + bias) + softplus_fast(u1[r] + bias);
        v += __shfl_xor(v, 16);
        v += __shfl_xor(v, 32);
        if ((lane >> 4) == 0 && j < 200) atomicAdd(&ws[j], v);
    }
}

// ---- y2 = (z @ W2.T + b2) * log2e with z computed inline from colsums ----
// z[s][d] = inv*ws[d] + inv*ws[100+d]*eps[s][d]; removes middle_kernel dispatch.
__global__ __launch_bounds__(256) void y2z_kernel(
    const float* __restrict__ W2, const float* __restrict__ b2,
    const float* __restrict__ eps, float* __restrict__ ws)
{
    int wid  = (int)((blockIdx.x * 256 + threadIdx.x) >> 6);
    int lane = threadIdx.x & 63;
    if (wid >= NS * DIN) return;
    int s = wid / DIN, i = wid % DIN;
    const float inv = 1.f / (float)NROWS;
    const float* wr = W2 + (size_t)i * DZ;
    const float* er = eps + (size_t)s * DZ;
    float p = 0.f;
    for (int d = lane; d < DZ; d += 64) {
        float zd = inv * (ws[d] + ws[100 + d] * er[d]);
        p += zd * wr[d];
    }
#pragma unroll
    for (int off = 32; off > 0; off >>= 1) p += __shfl_xor(p, off);
    if (lane == 0) ws[WS_Y2 + wid] = (p + b2[i]) * 1.4426950408889634f;
}

// ---- pv + fused finalization (last block computes Dkl + output) ----
// MFMA-certified bound: sum_i max(u,0) = 0.5*(n.y + |n|.|y|), u=(1-2x)*y2 (log2).
// bnd >= 45 => p < 2^-43 << ulp(0.001)/2 => term == ln(0.001) exactly.
__global__ __launch_bounds__(256, 4) void pv_final_kernel(
    const float* __restrict__ x, float* __restrict__ ws,
    const float* __restrict__ eps, float* __restrict__ out, int nblocks)
{
    __shared__ ushort_t yf[KTILES * 512];   // y2 B-frags (bf16)
    __shared__ ushort_t ya[KTILES * 512];   // |y2| B-frags
    __shared__ float bsum;
    __shared__ int lastflag;
    __shared__ float dred[256];
    const int tid = threadIdx.x;
    const int lane = tid & 63, w = tid >> 6;

    for (int idx = tid; idx < KTILES * 64; idx += 256) {
        int kt = idx >> 6, l = idx & 63;
        int ss = l & 15, k0 = kt * 32 + (l >> 4) * 8;
        uint4 o = make_uint4(0u, 0u, 0u, 0u), oa = o;
        if (ss < NS && k0 < DIN) {
            const float* src = ws + WS_Y2 + ss * DIN + k0;
            float4 a = *(const float4*)src, b = *(const float4*)(src + 4);
            o.x = pack2(a.x, a.y); o.y = pack2(a.z, a.w);
            o.z = pack2(b.x, b.y); o.w = pack2(b.z, b.w);
            oa.x = o.x & 0x7FFF7FFFu; oa.y = o.y & 0x7FFF7FFFu;
            oa.z = o.z & 0x7FFF7FFFu; oa.w = o.w & 0x7FFF7FFFu;
        }
        *(uint4*)(yf + (size_t)idx * 8) = o;
        *(uint4*)(ya + (size_t)idx * 8) = oa;
    }
    if (tid == 0) { bsum = 0.f; lastflag = 0; }
    __syncthreads();

    const int tile = blockIdx.x * 4 + w;       // 1024 tiles of 16 rows
    const int row  = tile * 16 + (lane & 15);
    const int kc   = lane >> 4;
    const int s    = lane & 15;
    const float* xp = x + (size_t)row * DIN;
    const float L001 = -6.90775527898f;        // ln(0.001f)

    f32x4 acc0 = (f32x4){0.f, 0.f, 0.f, 0.f};
    f32x4 acc1 = (f32x4){0.f, 0.f, 0.f, 0.f};
    float4 a0A, a1A, a0B, a1B;

    auto loadA = [&](int kt, float4& a0, float4& a1) {
        int k0 = kt * 32 + kc * 8;
        if (k0 + 8 > DIN) k0 = 768;            // junk ok: y frags zero there
        a0 = *(const float4*)(xp + k0);
        a1 = *(const float4*)(xp + k0 + 4);
    };
    auto comp = [&](int kt, const float4& a0, const float4& a1) {
        bf16x8 nf; unsigned* p = (unsigned*)&nf;
        p[0] = pack2(1.f - 2.f * a0.x, 1.f - 2.f * a0.y);
        p[1] = pack2(1.f - 2.f * a0.z, 1.f - 2.f * a0.w);
        p[2] = pack2(1.f - 2.f * a1.x, 1.f - 2.f * a1.y);
        p[3] = pack2(1.f - 2.f * a1.z, 1.f - 2.f * a1.w);
        bf16x8 na; unsigned* q = (unsigned*)&na;
        q[0] = p[0] & 0x7FFF7FFFu; q[1] = p[1] & 0x7FFF7FFFu;
        q[2] = p[2] & 0x7FFF7FFFu; q[3] = p[3] & 0x7FFF7FFFu;
        bf16x8 fy = *(const bf16x8*)(yf + (size_t)kt * 512 + lane * 8);
        bf16x8 fa = *(const bf16x8*)(ya + (size_t)kt * 512 + lane * 8);
        acc0 = __builtin_amdgcn_mfma_f32_16x16x32_bf16(nf, fy, acc0, 0, 0, 0);
        acc1 = __builtin_amdgcn_mfma_f32_16x16x32_bf16(na, fa, acc1, 0, 0, 0);
    };

    loadA(0, a0A, a1A);
    for (int i = 0; i < 12; ++i) {
        loadA(2 * i + 1, a0B, a1B);
        comp(2 * i, a0A, a1A);
        loadA(2 * i + 2, a0A, a1A);
        comp(2 * i + 1, a0B, a1B);
    }
    comp(24, a0A, a1A);

    float bnd[4];
#pragma unroll
    for (int r = 0; r < 4; ++r) bnd[r] = 0.5f * (acc0[r] + acc1[r]);

    float wsum;
    bool lslow = (s < NS) &&
        (fminf(fminf(bnd[0], bnd[1]), fminf(bnd[2], bnd[3])) < BND_THR);
    unsigned long long m = __ballot(lslow);
    if (m == 0ull) {
        wsum = 160.f * L001;                   // 16 rows x 10 samples, all certified
    } else {
        int nslow = 0;
        float slowsum = 0.f;
#pragma unroll
        for (int r = 0; r < 4; ++r) {
            unsigned long long mr = __ballot((s < NS) && (bnd[r] < BND_THR));
            nslow += (int)__popcll(mr);
            while (mr) {
                int src = (int)__ffsll(mr) - 1; mr &= (mr - 1);
                int ss = src & 15;
                int rrow = tile * 16 + (src >> 4) * 4 + r;
                const float* xq = x + (size_t)rrow * DIN;
                const float* yq = ws + WS_Y2 + ss * DIN;
                float a = 0.f;
                for (int i = lane; i < DIN; i += 64)
                    a -= __builtin_amdgcn_logf(
                        1.f + __builtin_amdgcn_exp2f((1.f - 2.f * xq[i]) * yq[i]));
#pragma unroll
                for (int off = 32; off > 0; off >>= 1) a += __shfl_xor(a, off);
                slowsum += __logf(__builtin_amdgcn_exp2f(a) + 0.001f);
            }
        }
        wsum = (float)(160 - nslow) * L001 + slowsum;
    }
    if (lane == 0) atomicAdd(&bsum, wsum);
    __syncthreads();

    // ---- completion protocol: last block finalizes ----
    if (tid == 0) {
        atomicAdd(&ws[200], bsum);
        __threadfence();                       // publish before counting
        unsigned old = atomicAdd((unsigned*)&ws[202], 1u);
        if (old == (unsigned)(nblocks - 1)) lastflag = 1;
    }
    __syncthreads();
    if (lastflag) {
        __threadfence();                       // acquire all blocks' sums
        float contrib = 0.f;
        if (tid < DZ) {
            const float inv = 1.f / (float)NROWS;
            float mm = ws[tid] * inv;
            float cc = ws[100 + tid] * inv;
            contrib = 0.5f * __logf(cc);
#pragma unroll
            for (int ss2 = 0; ss2 < NS; ++ss2) {
                float e = eps[ss2 * DZ + tid];
                float zz = mm + cc * e;
                contrib += (0.5f * cc * e * e - 0.5f * zz * zz) * (1.f / NS);
            }
        }
        dred[tid] = contrib;
        __syncthreads();
        for (int off = 128; off > 0; off >>= 1) {
            if (tid < off) dred[tid] += dred[tid + off];
            __syncthreads();
        }
        if (tid == 0) {
            float S = atomicAdd(&ws[200], 0.f);    // coherent read of final sum
            float E = S * (1.f / ((float)NROWS * (float)NS));
            out[0] = -(E + dred[0]);
        }
    }
}

extern "C" void kernel_launch(void* const* d_in, const int* in_sizes, int n_in,
                              void* d_out, int out_size, void* d_ws, size_t ws_size,
                              hipStream_t stream)
{
    const float* x   = (const float*)d_in[0];
    const float* W0  = (const float*)d_in[1];
    const float* b0  = (const float*)d_in[2];
    const float* W1  = (const float*)d_in[3];
    const float* b1  = (const float*)d_in[4];
    const float* W2  = (const float*)d_in[5];
    const float* b2  = (const float*)d_in[6];
    const float* eps = (const float*)d_in[7];
    float* out = (float*)d_out;
    float* ws  = (float*)d_ws;
    ushort_t* Wb = (ushort_t*)((char*)d_ws + WB_OFF_BYTES);

    wb_kernel<<<(KTILES * NCT * 64 + 255) / 256, 256, 0, stream>>>(W0, W1, Wb, ws);
    colmean_f<<<NROWS / 32, 512, 0, stream>>>(x, Wb, b0, b1, ws);
    y2z_kernel<<<(NS * DIN * 64) / 256, 256, 0, stream>>>(W2, b2, eps, ws);
    pv_final_kernel<<<256, 256, 0, stream>>>(x, ws, eps, out, 256);
}

// Round 14
// 57.763 us; speedup vs baseline: 1.8601x; 1.0409x over previous
//
#include <hip/hip_runtime.h>
#include <hip/hip_bf16.h>
#include <math.h>

#define NROWS 16384
#define DIN   784
#define DZ    100
#define NS    10
#define NCT   16           // 16 col-tiles x 16 = 256 cols (200 real + 56 zero pad)
#define KTILES 25          // 25 * 32 = 800 >= 784, tail frags zeroed
#define BND_THR 45.0f
#define KTPAD 520          // kt-stride in ushorts (1040B): spreads stage writes over banks

typedef unsigned short ushort_t;
typedef short bf16x8 __attribute__((ext_vector_type(8)));
typedef float f32x4  __attribute__((ext_vector_type(4)));

// ws layout:
//  floats [0..199] colsum softplus (atomic)  [200] pv log-sum  [202] done-counter
//  floats [208..8047] y2[s][i] = y*log2e
//  byte 64KB..: Wb bf16 frag-swizzled W, 25*16*512 ushorts (400 KB)
#define WS_Y2 208
#define WB_OFF_BYTES (64u * 1024u)

__device__ __forceinline__ float softplus_fast(float v) {
    // ln(1+e^v) = (max(t,0) + log2(1+2^-|t|)) * ln2, t = v*log2e  (v_exp/v_log pipes)
    float t = v * 1.44269504088896f;
    return (fmaxf(t, 0.f)
            + __builtin_amdgcn_logf(1.f + __builtin_amdgcn_exp2f(-fabsf(t))))
           * 0.69314718055995f;
}
__device__ __forceinline__ unsigned pack2(float lo, float hi) {
    float2 f2; f2.x = lo; f2.y = hi;
    __hip_bfloat162 h2 = __float22bfloat162_rn(f2);
    return *reinterpret_cast<unsigned*>(&h2);
}

// ---- W -> bf16 B-frags + ws zero (absorbs the memset dispatch) ----
// Wb[((kt*16 + ct)*64 + l)*8 + j] = W[ct*16 + (l&15)][kt*32 + (l>>4)*8 + j]
__global__ __launch_bounds__(256) void wb_kernel(
    const float* __restrict__ W0, const float* __restrict__ W1,
    ushort_t* __restrict__ Wb, float* __restrict__ ws)
{
    if (blockIdx.x == 0) ws[threadIdx.x] = 0.f;    // [0..255]: sums + counter
    int t = blockIdx.x * 256 + threadIdx.x;
    if (t >= KTILES * NCT * 64) return;
    int kt = t >> 10;
    int r  = t & 1023;
    int ct = r >> 6, l = r & 63;
    int col = ct * 16 + (l & 15);
    int k0  = kt * 32 + (l >> 4) * 8;
    uint4 o = make_uint4(0u, 0u, 0u, 0u);
    if (col < 200 && k0 < DIN) {
        const float* src = (col < 100 ? W0 + (size_t)col * DIN
                                      : W1 + (size_t)(col - 100) * DIN) + k0;
        float4 a = *(const float4*)src;
        float4 b = *(const float4*)(src + 4);
        o.x = pack2(a.x, a.y); o.y = pack2(a.z, a.w);
        o.z = pack2(b.x, b.y); o.w = pack2(b.z, b.w);
    }
    *(uint4*)(Wb + (size_t)t * 8) = o;
}

// ---- colmean g: BM=64, padded-LDS stage + barrier-free K-loop ----
// 256 blocks x 1024 thr (16 waves). Block = 64 rows x all 16 col-tiles.
// Stage: coalesced x reads -> bf16 A-frags in LDS (kt-stride 1040B -> bank-spread
// writes), ONE barrier. K-loop: wave w = rowtile (w>>2) x col-quarter (w&3);
// per kt: 1 ds_read_b128 + 4 coalesced B loads (L1/L2) + 4 MFMA; reg dbuf.
__global__ __launch_bounds__(1024) void colmean_g(
    const float* __restrict__ x, const ushort_t* __restrict__ Wb,
    const float* __restrict__ b0, const float* __restrict__ b1,
    float* __restrict__ ws)
{
    __shared__ ushort_t xls[4 * KTILES * KTPAD];   // 104 KB
    __shared__ float red2[12][4][16];              // 3 KB cross-rt reduce
    const int tid = threadIdx.x;
    const int lane = tid & 63, w = tid >> 6;
    const int row0 = blockIdx.x * 64;

    // ---- stage ----
    for (int slot = tid; slot < 6400; slot += 1024) {  // slot = r*100 + kt*4 + kc
        int r  = slot / 100;
        int sl = slot - r * 100;
        int kt = sl >> 2, kc = sl & 3;
        int k0 = kt * 32 + kc * 8;
        uint4 o = make_uint4(0u, 0u, 0u, 0u);
        if (k0 + 8 <= DIN) {
            const float* src = x + (size_t)(row0 + r) * DIN + k0;
            float4 a = *(const float4*)src, b = *(const float4*)(src + 4);
            o.x = pack2(a.x, a.y); o.y = pack2(a.z, a.w);
            o.z = pack2(b.x, b.y); o.w = pack2(b.z, b.w);
        }
        int l = (kc << 4) | (r & 15);
        *(uint4*)&xls[((size_t)(r >> 4) * KTILES + kt) * KTPAD + l * 8] = o;
    }
    __syncthreads();

    // ---- K-loop ----
    const int rt = w >> 2, ct0 = (w & 3) * 4;
    const ushort_t* ap  = xls + (size_t)rt * KTILES * KTPAD + lane * 8;
    const ushort_t* wbp = Wb + (size_t)ct0 * 512 + lane * 8;

    f32x4 acc[4];
#pragma unroll
    for (int jj = 0; jj < 4; ++jj) acc[jj] = (f32x4){0.f, 0.f, 0.f, 0.f};

    bf16x8 Aa, Ab;
    uint4  Ba[4], Bb[4];

    auto ld = [&](int kt, bf16x8& A, uint4 (&B)[4]) {
        A = *(const bf16x8*)(ap + (size_t)kt * KTPAD);
#pragma unroll
        for (int jj = 0; jj < 4; ++jj)
            B[jj] = *(const uint4*)(wbp + (size_t)kt * 8192 + jj * 512);
    };
    auto cp = [&](const bf16x8& A, const uint4 (&B)[4]) {
#pragma unroll
        for (int jj = 0; jj < 4; ++jj)
            acc[jj] = __builtin_amdgcn_mfma_f32_16x16x32_bf16(
                A, *(const bf16x8*)&B[jj], acc[jj], 0, 0, 0);
    };

    ld(0, Aa, Ba);
    for (int i = 0; i < 12; ++i) {
        ld(2 * i + 1, Ab, Bb);
        cp(Aa, Ba);
        ld(2 * i + 2, Aa, Ba);
        cp(Ab, Bb);
    }
    cp(Aa, Ba);                            // kt = 24

    // ---- epilogue: softplus + 16-row shfl reduce + cross-rt LDS reduce ----
    float vj[4];
#pragma unroll
    for (int jj = 0; jj < 4; ++jj) {
        int j = (ct0 + jj) * 16 + (lane & 15);
        float bias = (j < 100) ? b0[j] : ((j < 200) ? b1[j - 100] : 0.f);
        float v = 0.f;
#pragma unroll
        for (int r = 0; r < 4; ++r) v += softplus_fast(acc[jj][r] + bias);
        v += __shfl_xor(v, 16);
        v += __shfl_xor(v, 32);
        vj[jj] = v;
    }
    if (rt > 0 && (lane >> 4) == 0) {
#pragma unroll
        for (int jj = 0; jj < 4; ++jj)
            red2[(rt - 1) * 4 + (w & 3)][jj][lane & 15] = vj[jj];
    }
    __syncthreads();
    if (rt == 0 && (lane >> 4) == 0) {
#pragma unroll
        for (int jj = 0; jj < 4; ++jj) {
            int j = (ct0 + jj) * 16 + (lane & 15);
            float v = vj[jj]
                    + red2[0 + (w & 3)][jj][lane & 15]
                    + red2[4 + (w & 3)][jj][lane & 15]
                    + red2[8 + (w & 3)][jj][lane & 15];
            if (j < 200) atomicAdd(&ws[j], v);
        }
    }
}

// ---- y2 = (z @ W2.T + b2) * log2e with z computed inline from colsums ----
__global__ __launch_bounds__(256) void y2z_kernel(
    const float* __restrict__ W2, const float* __restrict__ b2,
    const float* __restrict__ eps, float* __restrict__ ws)
{
    int wid  = (int)((blockIdx.x * 256 + threadIdx.x) >> 6);
    int lane = threadIdx.x & 63;
    if (wid >= NS * DIN) return;
    int s = wid / DIN, i = wid % DIN;
    const float inv = 1.f / (float)NROWS;
    const float* wr = W2 + (size_t)i * DZ;
    const float* er = eps + (size_t)s * DZ;
    float p = 0.f;
    for (int d = lane; d < DZ; d += 64) {
        float zd = inv * (ws[d] + ws[100 + d] * er[d]);
        p += zd * wr[d];
    }
#pragma unroll
    for (int off = 32; off > 0; off >>= 1) p += __shfl_xor(p, off);
    if (lane == 0) ws[WS_Y2 + wid] = (p + b2[i]) * 1.4426950408889634f;
}

// ---- pv + fused finalization (last block computes Dkl + output) ----
// MFMA-certified bound: sum_i max(u,0) = 0.5*(n.y + |n|.|y|), u=(1-2x)*y2 (log2).
// bnd >= 45 => p < 2^-43 << ulp(0.001)/2 => term == ln(0.001) exactly.
__global__ __launch_bounds__(256, 4) void pv_final_kernel(
    const float* __restrict__ x, float* __restrict__ ws,
    const float* __restrict__ eps, float* __restrict__ out, int nblocks)
{
    __shared__ ushort_t yf[KTILES * 512];   // y2 B-frags (bf16)
    __shared__ ushort_t ya[KTILES * 512];   // |y2| B-frags
    __shared__ float bsum;
    __shared__ int lastflag;
    __shared__ float dred[256];
    const int tid = threadIdx.x;
    const int lane = tid & 63, w = tid >> 6;

    for (int idx = tid; idx < KTILES * 64; idx += 256) {
        int kt = idx >> 6, l = idx & 63;
        int ss = l & 15, k0 = kt * 32 + (l >> 4) * 8;
        uint4 o = make_uint4(0u, 0u, 0u, 0u), oa = o;
        if (ss < NS && k0 < DIN) {
            const float* src = ws + WS_Y2 + ss * DIN + k0;
            float4 a = *(const float4*)src, b = *(const float4*)(src + 4);
            o.x = pack2(a.x, a.y); o.y = pack2(a.z, a.w);
            o.z = pack2(b.x, b.y); o.w = pack2(b.z, b.w);
            oa.x = o.x & 0x7FFF7FFFu; oa.y = o.y & 0x7FFF7FFFu;
            oa.z = o.z & 0x7FFF7FFFu; oa.w = o.w & 0x7FFF7FFFu;
        }
        *(uint4*)(yf + (size_t)idx * 8) = o;
        *(uint4*)(ya + (size_t)idx * 8) = oa;
    }
    if (tid == 0) { bsum = 0.f; lastflag = 0; }
    __syncthreads();

    const int tile = blockIdx.x * 4 + w;       // 1024 tiles of 16 rows
    const int row  = tile * 16 + (lane & 15);
    const int kc   = lane >> 4;
    const int s    = lane & 15;
    const float* xp = x + (size_t)row * DIN;
    const float L001 = -6.90775527898f;        // ln(0.001f)

    f32x4 acc0 = (f32x4){0.f, 0.f, 0.f, 0.f};
    f32x4 acc1 = (f32x4){0.f, 0.f, 0.f, 0.f};
    float4 a0A, a1A, a0B, a1B;

    auto loadA = [&](int kt, float4& a0, float4& a1) {
        int k0 = kt * 32 + kc * 8;
        if (k0 + 8 > DIN) k0 = 768;            // junk ok: y frags zero there
        a0 = *(const float4*)(xp + k0);
        a1 = *(const float4*)(xp + k0 + 4);
    };
    auto comp = [&](int kt, const float4& a0, const float4& a1) {
        bf16x8 nf; unsigned* p = (unsigned*)&nf;
        p[0] = pack2(1.f - 2.f * a0.x, 1.f - 2.f * a0.y);
        p[1] = pack2(1.f - 2.f * a0.z, 1.f - 2.f * a0.w);
        p[2] = pack2(1.f - 2.f * a1.x, 1.f - 2.f * a1.y);
        p[3] = pack2(1.f - 2.f * a1.z, 1.f - 2.f * a1.w);
        bf16x8 na; unsigned* q = (unsigned*)&na;
        q[0] = p[0] & 0x7FFF7FFFu; q[1] = p[1] & 0x7FFF7FFFu;
        q[2] = p[2] & 0x7FFF7FFFu; q[3] = p[3] & 0x7FFF7FFFu;
        bf16x8 fy = *(const bf16x8*)(yf + (size_t)kt * 512 + lane * 8);
        bf16x8 fa = *(const bf16x8*)(ya + (size_t)kt * 512 + lane * 8);
        acc0 = __builtin_amdgcn_mfma_f32_16x16x32_bf16(nf, fy, acc0, 0, 0, 0);
        acc1 = __builtin_amdgcn_mfma_f32_16x16x32_bf16(na, fa, acc1, 0, 0, 0);
    };

    loadA(0, a0A, a1A);
    for (int i = 0; i < 12; ++i) {
        loadA(2 * i + 1, a0B, a1B);
        comp(2 * i, a0A, a1A);
        loadA(2 * i + 2, a0A, a1A);
        comp(2 * i + 1, a0B, a1B);
    }
    comp(24, a0A, a1A);

    float bnd[4];
#pragma unroll
    for (int r = 0; r < 4; ++r) bnd[r] = 0.5f * (acc0[r] + acc1[r]);

    float wsum;
    bool lslow = (s < NS) &&
        (fminf(fminf(bnd[0], bnd[1]), fminf(bnd[2], bnd[3])) < BND_THR);
    unsigned long long m = __ballot(lslow);
    if (m == 0ull) {
        wsum = 160.f * L001;                   // 16 rows x 10 samples, all certified
    } else {
        int nslow = 0;
        float slowsum = 0.f;
#pragma unroll
        for (int r = 0; r < 4; ++r) {
            unsigned long long mr = __ballot((s < NS) && (bnd[r] < BND_THR));
            nslow += (int)__popcll(mr);
            while (mr) {
                int src = (int)__ffsll(mr) - 1; mr &= (mr - 1);
                int ss = src & 15;
                int rrow = tile * 16 + (src >> 4) * 4 + r;
                const float* xq = x + (size_t)rrow * DIN;
                const float* yq = ws + WS_Y2 + ss * DIN;
                float a = 0.f;
                for (int i = lane; i < DIN; i += 64)
                    a -= __builtin_amdgcn_logf(
                        1.f + __builtin_amdgcn_exp2f((1.f - 2.f * xq[i]) * yq[i]));
#pragma unroll
                for (int off = 32; off > 0; off >>= 1) a += __shfl_xor(a, off);
                slowsum += __logf(__builtin_amdgcn_exp2f(a) + 0.001f);
            }
        }
        wsum = (float)(160 - nslow) * L001 + slowsum;
    }
    if (lane == 0) atomicAdd(&bsum, wsum);
    __syncthreads();

    // ---- completion protocol: last block finalizes ----
    if (tid == 0) {
        atomicAdd(&ws[200], bsum);
        __threadfence();                       // publish before counting
        unsigned old = atomicAdd((unsigned*)&ws[202], 1u);
        if (old == (unsigned)(nblocks - 1)) lastflag = 1;
    }
    __syncthreads();
    if (lastflag) {
        __threadfence();                       // acquire all blocks' sums
        float contrib = 0.f;
        if (tid < DZ) {
            const float inv = 1.f / (float)NROWS;
            float mm = ws[tid] * inv;
            float cc = ws[100 + tid] * inv;
            contrib = 0.5f * __logf(cc);
#pragma unroll
            for (int ss2 = 0; ss2 < NS; ++ss2) {
                float e = eps[ss2 * DZ + tid];
                float zz = mm + cc * e;
                contrib += (0.5f * cc * e * e - 0.5f * zz * zz) * (1.f / NS);
            }
        }
        dred[tid] = contrib;
        __syncthreads();
        for (int off = 128; off > 0; off >>= 1) {
            if (tid < off) dred[tid] += dred[tid + off];
            __syncthreads();
        }
        if (tid == 0) {
            float S = atomicAdd(&ws[200], 0.f);    // coherent read of final sum
            float E = S * (1.f / ((float)NROWS * (float)NS));
            out[0] = -(E + dred[0]);
        }
    }
}

extern "C" void kernel_launch(void* const* d_in, const int* in_sizes, int n_in,
                              void* d_out, int out_size, void* d_ws, size_t ws_size,
                              hipStream_t stream)
{
    const float* x   = (const float*)d_in[0];
    const float* W0  = (const float*)d_in[1];
    const float* b0  = (const float*)d_in[2];
    const float* W1  = (const float*)d_in[3];
    const float* b1  = (const float*)d_in[4];
    const float* W2  = (const float*)d_in[5];
    const float* b2  = (const float*)d_in[6];
    const float* eps = (const float*)d_in[7];
    float* out = (float*)d_out;
    float* ws  = (float*)d_ws;
    ushort_t* Wb = (ushort_t*)((char*)d_ws + WB_OFF_BYTES);

    wb_kernel<<<(KTILES * NCT * 64 + 255) / 256, 256, 0, stream>>>(W0, W1, Wb, ws);
    colmean_g<<<NROWS / 64, 1024, 0, stream>>>(x, Wb, b0, b1, ws);
    y2z_kernel<<<(NS * DIN * 64) / 256, 256, 0, stream>>>(W2, b2, eps, ws);
    pv_final_kernel<<<256, 256, 0, stream>>>(x, ws, eps, out, 256);
}